// Round 2
// baseline (361.512 us; speedup 1.0000x reference)
//
#include <hip/hip_runtime.h>
#include <math.h>

// Problem dims (hardcoded per reference): B=2, H=256, W=256, C=64,
// heads=8, dh=64, hd=512, dim_out=64, n=65536/batch, n_ds=16384/batch.
//
// Algebra: with q,k l2-normalized over the TOKEN axis,
//   attn[b,h,i,j] = (Wk[:,hi]^T G[b] Wq[:,hj]) / (||k_i|| ||q_j||) * rescale[h]
// where G[b] = Xd^T Xd (64x64 Gram of 2x2-avg-pooled input).
//   out_c = x @ W_eff[b] + bproj,  W_eff[b] = Wv @ blockdiag_h(attn_h^T) @ Wproj (64x64)
//   p     = x @ W_pos + bc1d,      W_pos   = Wv @ Wc1d                        (64x64)
//   out   = out_c + dwconv3x3(gelu(dwconv3x3(p, Wpe1)), Wpe2)
//
// DTYPE-ADAPTIVE: inputs may arrive as fp32 (per reference) or bf16 (if the
// harness downcast the problem). rescale == ones(8) exactly, so its first u16
// is 0x3F80 iff bf16, 0x0000 iff fp32. k_convert canonicalizes all inputs to
// bf16 ws buffers; k_final branches on the same tag for the output format.

typedef unsigned short u16;
typedef unsigned int u32;

__device__ __forceinline__ float bf2f(u16 h) {
    return __uint_as_float(((u32)h) << 16);
}
__device__ __forceinline__ u16 f2bf(float f) {
    u32 u = __float_as_uint(f);
    u32 r = (u + 0x7fffu + ((u >> 16) & 1u)) >> 16;
    return (u16)r;
}
__device__ __forceinline__ void unpack8(uint4 v, float* f) {
    u32 a[4] = {v.x, v.y, v.z, v.w};
#pragma unroll
    for (int i = 0; i < 4; ++i) {
        f[2 * i]     = __uint_as_float(a[i] << 16);
        f[2 * i + 1] = __uint_as_float(a[i] & 0xffff0000u);
    }
}

// ---------------------------------------------------------------------------
// K0: canonicalize all inputs to bf16. One thread per element-PAIR (u32 out).
// Sizes (elems): x 8388608, Wq/Wk/Wv 32768, rescale 8, Wproj 32768, bproj 64,
// Wc1d 32768, bc1d 64, Wpe1/Wpe2 576. Total 8553736 elems = 4276868 pairs.
__global__ __launch_bounds__(256) void k_convert(
    const u32* __restrict__ x,  const u32* __restrict__ wq, const u32* __restrict__ wk,
    const u32* __restrict__ wv, const u32* __restrict__ rs, const u32* __restrict__ wp,
    const u32* __restrict__ bp, const u32* __restrict__ wc, const u32* __restrict__ bc,
    const u32* __restrict__ p1, const u32* __restrict__ p2, u32* __restrict__ dst) {
    u32 pid = blockIdx.x * 256 + threadIdx.x;
    if (pid >= 4276868u) return;
    const u32* src; u32 p;
    if      (pid < 4194304u) { src = x;  p = pid; }
    else if (pid < 4210688u) { src = wq; p = pid - 4194304u; }
    else if (pid < 4227072u) { src = wk; p = pid - 4210688u; }
    else if (pid < 4243456u) { src = wv; p = pid - 4227072u; }
    else if (pid < 4243460u) { src = rs; p = pid - 4243456u; }
    else if (pid < 4259844u) { src = wp; p = pid - 4243460u; }
    else if (pid < 4259876u) { src = bp; p = pid - 4259844u; }
    else if (pid < 4276260u) { src = wc; p = pid - 4259876u; }
    else if (pid < 4276292u) { src = bc; p = pid - 4276260u; }
    else if (pid < 4276580u) { src = p1; p = pid - 4276292u; }
    else                     { src = p2; p = pid - 4276580u; }

    u16 tag = ((const u16*)rs)[0];            // 0x3F80 => already bf16
    if (tag == 0x3F80u) {
        dst[pid] = src[p];
    } else {
        const float* sf = (const float*)src;
        float f0 = sf[2 * p], f1 = sf[2 * p + 1];
        dst[pid] = (u32)f2bf(f0) | ((u32)f2bf(f1) << 16);
    }
}

// ---------------------------------------------------------------------------
// K1: fused 2x2 avg-pool + Gram partials. 256 blocks (2 batches x 128 pooled
// rows); each block handles one pooled row (128 tokens), each thread owns a
// 4x4 tile of the 64x64 Gram.
__global__ __launch_bounds__(256) void k_pool_gram(const u16* __restrict__ x,
                                                   float* __restrict__ partials) {
    int blk = blockIdx.x;       // 0..255
    int b   = blk >> 7;
    int py  = blk & 127;
    int t   = threadIdx.x;
    int g   = t >> 6;           // token-in-group 0..3
    int ch  = t & 63;
    int r0  = (t >> 4) << 2;    // 0,4,..,60
    int c0  = (t & 15) << 2;

    __shared__ float xv[4][64];
    float acc[4][4] = {{0.f}};
    const size_t rowbase = ((size_t)(b * 256 + 2 * py)) * 256 * 64;

    for (int tg = 0; tg < 32; ++tg) {
        int px = tg * 4 + g;
        size_t base = rowbase + (size_t)(2 * px) * 64 + ch;
        float v0 = bf2f(x[base]);
        float v1 = bf2f(x[base + 64]);
        float v2 = bf2f(x[base + 256 * 64]);
        float v3 = bf2f(x[base + 256 * 64 + 64]);
        __syncthreads();
        xv[g][ch] = 0.25f * (v0 + v1 + v2 + v3);
        __syncthreads();
#pragma unroll
        for (int gl = 0; gl < 4; ++gl) {
            float a0 = xv[gl][r0], a1 = xv[gl][r0 + 1], a2 = xv[gl][r0 + 2], a3 = xv[gl][r0 + 3];
            float b0 = xv[gl][c0], b1 = xv[gl][c0 + 1], b2 = xv[gl][c0 + 2], b3 = xv[gl][c0 + 3];
            acc[0][0] += a0 * b0; acc[0][1] += a0 * b1; acc[0][2] += a0 * b2; acc[0][3] += a0 * b3;
            acc[1][0] += a1 * b0; acc[1][1] += a1 * b1; acc[1][2] += a1 * b2; acc[1][3] += a1 * b3;
            acc[2][0] += a2 * b0; acc[2][1] += a2 * b1; acc[2][2] += a2 * b2; acc[2][3] += a2 * b3;
            acc[3][0] += a3 * b0; acc[3][1] += a3 * b1; acc[3][2] += a3 * b2; acc[3][3] += a3 * b3;
        }
    }
    float* out = partials + (size_t)blk * 4096;
#pragma unroll
    for (int i = 0; i < 4; ++i)
#pragma unroll
        for (int j = 0; j < 4; ++j)
            out[(r0 + i) * 64 + (c0 + j)] = acc[i][j];
}

// K2: reduce 128 partials per batch -> G[2][64][64]
__global__ __launch_bounds__(256) void k_gram_reduce(const float* __restrict__ partials,
                                                     float* __restrict__ G) {
    int gid = blockIdx.x * 256 + threadIdx.x;   // 0..8191
    int b = gid >> 12;
    int e = gid & 4095;
    float s = 0.f;
    for (int p = 0; p < 128; ++p)
        s += partials[((size_t)(b * 128 + p)) * 4096 + e];
    G[b * 4096 + e] = s;
}

// K3: T = G @ Wq, U = G @ Wk   ([2][64][512] each, fp32)
__global__ __launch_bounds__(256) void k_gwqk(const float* __restrict__ G,
                                              const u16* __restrict__ Wq,
                                              const u16* __restrict__ Wk,
                                              float* __restrict__ T,
                                              float* __restrict__ U) {
    int gid = blockIdx.x * 256 + threadIdx.x;   // 0..131071
    int j   = gid & 511;
    int c   = (gid >> 9) & 63;
    int b   = (gid >> 15) & 1;
    int sel = gid >> 16;
    const u16* W = sel ? Wk : Wq;
    float s = 0.f;
    const float* Grow = G + b * 4096 + c * 64;
    for (int k = 0; k < 64; ++k)
        s += Grow[k] * bf2f(W[k * 512 + j]);
    float* D = sel ? U : T;
    D[((size_t)(b * 64 + c)) * 512 + j] = s;
}

// K4: column norms  nq[b][j] = max(sqrt(Wq_j^T G Wq_j), 1e-12), same for nk
__global__ __launch_bounds__(256) void k_norms(const u16* __restrict__ Wq,
                                               const u16* __restrict__ Wk,
                                               const float* __restrict__ T,
                                               const float* __restrict__ U,
                                               float* __restrict__ nq,
                                               float* __restrict__ nk) {
    int gid = blockIdx.x * 256 + threadIdx.x;   // 0..2047
    int j   = gid & 511;
    int b   = (gid >> 9) & 1;
    int sel = gid >> 10;
    const u16* W   = sel ? Wk : Wq;
    const float* D = sel ? U : T;
    float s = 0.f;
    for (int c = 0; c < 64; ++c)
        s += bf2f(W[c * 512 + j]) * D[((size_t)(b * 64 + c)) * 512 + j];
    float n = fmaxf(sqrtf(fmaxf(s, 0.f)), 1e-12f);
    (sel ? nk : nq)[b * 512 + j] = n;
}

// K5: logits + row softmax -> attn[2][8][64][64]. One wave per row (b,h,i).
__global__ __launch_bounds__(256) void k_attn(const u16* __restrict__ Wk,
                                              const float* __restrict__ T,
                                              const float* __restrict__ nq,
                                              const float* __restrict__ nk,
                                              const u16* __restrict__ rescale,
                                              float* __restrict__ attn) {
    int t = threadIdx.x;
    int w = t >> 6;
    int j = t & 63;
    int r = blockIdx.x * 4 + w;   // 0..1023
    int b = r >> 9;
    int h = (r >> 6) & 7;
    int i = r & 63;

    float s = 0.f;
    for (int c = 0; c < 64; ++c)
        s += bf2f(Wk[c * 512 + h * 64 + i]) * T[((size_t)(b * 64 + c)) * 512 + h * 64 + j];
    float logit = s * bf2f(rescale[h]) / (nk[b * 512 + h * 64 + i] * nq[b * 512 + h * 64 + j]);

    float m = logit;
#pragma unroll
    for (int d = 32; d >= 1; d >>= 1) m = fmaxf(m, __shfl_xor(m, d, 64));
    float e = __expf(logit - m);
    float ssum = e;
#pragma unroll
    for (int d = 32; d >= 1; d >>= 1) ssum += __shfl_xor(ssum, d, 64);
    attn[((size_t)((b * 8 + h) * 64 + i)) * 64 + j] = e / ssum;
}

// K6: P[b][t][o] = sum_i attn[b,h(t),i,j(t)] * Wproj[h*64+i, o]
__global__ __launch_bounds__(256) void k_pmat(const float* __restrict__ attn,
                                              const u16* __restrict__ Wproj,
                                              float* __restrict__ P) {
    int gid = blockIdx.x * 256 + threadIdx.x;   // 0..65535
    int o  = gid & 63;
    int tt = (gid >> 6) & 511;
    int b  = gid >> 15;
    int h  = tt >> 6;
    int j  = tt & 63;
    float s = 0.f;
    for (int i = 0; i < 64; ++i)
        s += attn[((size_t)((b * 8 + h) * 64 + i)) * 64 + j] * bf2f(Wproj[(h * 64 + i) * 64 + o]);
    P[gid] = s;   // gid == b*32768 + tt*64 + o
}

// K7: W_eff[b] = Wv @ P[b] (64x64), W_pos = Wv @ Wc1d (64x64)
__global__ __launch_bounds__(256) void k_weff(const u16* __restrict__ Wv,
                                              const float* __restrict__ P,
                                              const u16* __restrict__ Wc1d,
                                              float* __restrict__ Weff,
                                              float* __restrict__ Wpos) {
    int gid = blockIdx.x * 256 + threadIdx.x;   // 0..12287
    if (gid < 8192) {
        int o = gid & 63;
        int c = (gid >> 6) & 63;
        int b = gid >> 12;
        float s = 0.f;
        for (int t = 0; t < 512; ++t)
            s += bf2f(Wv[c * 512 + t]) * P[(size_t)b * 32768 + t * 64 + o];
        Weff[b * 4096 + c * 64 + o] = s;
    } else {
        int g2 = gid - 8192;
        int o = g2 & 63;
        int c = g2 >> 6;
        float s = 0.f;
        for (int t = 0; t < 512; ++t)
            s += bf2f(Wv[c * 512 + t]) * bf2f(Wc1d[t * 64 + o]);
        Wpos[c * 64 + o] = s;
    }
}

// K8: p[n][c] = x[n][:] @ W_pos + bc1d  (bf16 out). 64 pixels/block,
// 4 threads/pixel x 16 output channels.
__global__ __launch_bounds__(256) void k_pmain(const u16* __restrict__ x,
                                               const float* __restrict__ Wpos,
                                               const u16* __restrict__ bc1d,
                                               u16* __restrict__ pbuf) {
    __shared__ float wsm[4096];
    for (int i = threadIdx.x; i < 4096; i += 256) wsm[i] = Wpos[i];
    __syncthreads();

    int t = threadIdx.x;
    size_t n = (size_t)blockIdx.x * 64 + (t >> 2);
    int og = (t & 3) * 16;

    const uint4* xp = (const uint4*)(x + n * 64);
    float xr[64];
#pragma unroll
    for (int i = 0; i < 8; ++i) { uint4 v = xp[i]; unpack8(v, &xr[i * 8]); }

    float acc[16] = {0.f};
#pragma unroll 4
    for (int k = 0; k < 64; ++k) {
        const float4* wr = (const float4*)(&wsm[k * 64 + og]);
        float xk = xr[k];
#pragma unroll
        for (int q = 0; q < 4; ++q) {
            float4 wv = wr[q];
            acc[q * 4 + 0] += xk * wv.x;
            acc[q * 4 + 1] += xk * wv.y;
            acc[q * 4 + 2] += xk * wv.z;
            acc[q * 4 + 3] += xk * wv.w;
        }
    }
    u32 packed[8];
#pragma unroll
    for (int q = 0; q < 8; ++q) {
        float f0 = acc[2 * q]     + bf2f(bc1d[og + 2 * q]);
        float f1 = acc[2 * q + 1] + bf2f(bc1d[og + 2 * q + 1]);
        packed[q] = (u32)f2bf(f0) | ((u32)f2bf(f1) << 16);
    }
    uint4* op = (uint4*)(pbuf + n * 64 + og);
    op[0] = make_uint4(packed[0], packed[1], packed[2], packed[3]);
    op[1] = make_uint4(packed[4], packed[5], packed[6], packed[7]);
}

// K9: t = gelu(dwconv3x3(p, Wpe1))  (bf16). 32 pixels/block, 8 ch/thread.
__global__ __launch_bounds__(256) void k_conv1(const u16* __restrict__ p,
                                               const u16* __restrict__ wpe1,
                                               u16* __restrict__ tbuf) {
    int t = threadIdx.x;
    int n = blockIdx.x * 32 + (t >> 3);
    int cg = (t & 7) * 8;
    int b  = n >> 16;
    int yy = (n >> 8) & 255;
    int xx = n & 255;

    float w[8][9];
#pragma unroll
    for (int j = 0; j < 8; ++j)
#pragma unroll
        for (int k = 0; k < 9; ++k) w[j][k] = bf2f(wpe1[(cg + j) * 9 + k]);

    float acc[8] = {0.f};
    for (int dy = -1; dy <= 1; ++dy) {
        int y2 = yy + dy;
        if ((unsigned)y2 >= 256u) continue;
        for (int dx = -1; dx <= 1; ++dx) {
            int x2 = xx + dx;
            if ((unsigned)x2 >= 256u) continue;
            const uint4* pp = (const uint4*)(p + ((size_t)(b * 65536 + y2 * 256 + x2)) * 64 + cg);
            float f[8];
            unpack8(pp[0], f);
            int tap = (dy + 1) * 3 + (dx + 1);
#pragma unroll
            for (int j = 0; j < 8; ++j) acc[j] += f[j] * w[j][tap];
        }
    }
    u32 packed[4];
#pragma unroll
    for (int q = 0; q < 4; ++q) {
        float v0 = acc[2 * q];
        float v1 = acc[2 * q + 1];
        v0 = 0.5f * v0 * (1.f + erff(v0 * 0.70710678118654752f));
        v1 = 0.5f * v1 * (1.f + erff(v1 * 0.70710678118654752f));
        packed[q] = (u32)f2bf(v0) | ((u32)f2bf(v1) << 16);
    }
    *((uint4*)(tbuf + (size_t)n * 64 + cg)) = make_uint4(packed[0], packed[1], packed[2], packed[3]);
}

// K10: out = x @ W_eff[b] + bproj + dwconv3x3(t, Wpe2). Output dtype adaptive.
__global__ __launch_bounds__(256) void k_final(const u16* __restrict__ x,
                                               const u16* __restrict__ tbuf,
                                               const float* __restrict__ Weff,
                                               const u16* __restrict__ wpe2,
                                               const u16* __restrict__ bproj,
                                               const u16* __restrict__ rs_raw,
                                               void* __restrict__ outv) {
    __shared__ float wsm[4096];
    size_t n0 = (size_t)blockIdx.x * 64;
    int b = (int)(n0 >> 16);
    for (int i = threadIdx.x; i < 4096; i += 256) wsm[i] = Weff[b * 4096 + i];
    __syncthreads();

    int t = threadIdx.x;
    size_t n = n0 + (t >> 2);
    int og = (t & 3) * 16;

    const uint4* xp = (const uint4*)(x + n * 64);
    float xr[64];
#pragma unroll
    for (int i = 0; i < 8; ++i) { uint4 v = xp[i]; unpack8(v, &xr[i * 8]); }

    float acc[16] = {0.f};
#pragma unroll 4
    for (int k = 0; k < 64; ++k) {
        const float4* wr = (const float4*)(&wsm[k * 64 + og]);
        float xk = xr[k];
#pragma unroll
        for (int q = 0; q < 4; ++q) {
            float4 wv = wr[q];
            acc[q * 4 + 0] += xk * wv.x;
            acc[q * 4 + 1] += xk * wv.y;
            acc[q * 4 + 2] += xk * wv.z;
            acc[q * 4 + 3] += xk * wv.w;
        }
    }

    int nn = (int)(n & 65535);
    int yy = nn >> 8;
    int xx = nn & 255;
    float accc[16] = {0.f};
    for (int dy = -1; dy <= 1; ++dy) {
        int y2 = yy + dy;
        if ((unsigned)y2 >= 256u) continue;
        for (int dx = -1; dx <= 1; ++dx) {
            int x2 = xx + dx;
            if ((unsigned)x2 >= 256u) continue;
            const uint4* tp = (const uint4*)(tbuf + ((size_t)(b * 65536 + y2 * 256 + x2)) * 64 + og);
            float f[16];
            unpack8(tp[0], f);
            unpack8(tp[1], f + 8);
            int tap = (dy + 1) * 3 + (dx + 1);
#pragma unroll
            for (int j = 0; j < 16; ++j)
                accc[j] += f[j] * bf2f(wpe2[(og + j) * 9 + tap]);
        }
    }

    float res[16];
#pragma unroll
    for (int j = 0; j < 16; ++j)
        res[j] = acc[j] + accc[j] + bf2f(bproj[og + j]);

    u16 tag = rs_raw[0];                       // 0x3F80 => bf16 problem
    if (tag == 0x3F80u) {
        u32 packed[8];
#pragma unroll
        for (int q = 0; q < 8; ++q)
            packed[q] = (u32)f2bf(res[2 * q]) | ((u32)f2bf(res[2 * q + 1]) << 16);
        uint4* op = (uint4*)((u16*)outv + n * 64 + og);
        op[0] = make_uint4(packed[0], packed[1], packed[2], packed[3]);
        op[1] = make_uint4(packed[4], packed[5], packed[6], packed[7]);
    } else {
        float4* of = (float4*)((float*)outv + n * 64 + og);
#pragma unroll
        for (int q = 0; q < 4; ++q)
            of[q] = make_float4(res[4 * q], res[4 * q + 1], res[4 * q + 2], res[4 * q + 3]);
    }
}

// ---------------------------------------------------------------------------
extern "C" void kernel_launch(void* const* d_in, const int* in_sizes, int n_in,
                              void* d_out, int out_size, void* d_ws, size_t ws_size,
                              hipStream_t stream) {
    char* w = (char*)d_ws;
    size_t off = 0;
    auto alloc = [&](size_t bytes) -> void* {
        void* p = w + off;
        off += (bytes + 255) & ~(size_t)255;
        return p;
    };
    // canonical bf16 copies of all inputs (contiguous, in input order)
    u16* cb = (u16*)alloc((size_t)8553736 * 2);
    u16* xb  = cb;
    u16* wqb = cb + 8388608;
    u16* wkb = wqb + 32768;
    u16* wvb = wkb + 32768;
    u16* rsb = wvb + 32768;
    u16* wpb = rsb + 8;
    u16* bpb = wpb + 32768;
    u16* wcb = bpb + 64;
    u16* bcb = wcb + 32768;
    u16* p1b = bcb + 64;
    u16* p2b = p1b + 576;

    float* partials = (float*)alloc((size_t)2 * 128 * 4096 * 4);
    float* G        = (float*)alloc((size_t)2 * 4096 * 4);
    float* T        = (float*)alloc((size_t)2 * 64 * 512 * 4);
    float* U        = (float*)alloc((size_t)2 * 64 * 512 * 4);
    float* nq       = (float*)alloc((size_t)2 * 512 * 4);
    float* nk       = (float*)alloc((size_t)2 * 512 * 4);
    float* attn     = (float*)alloc((size_t)2 * 8 * 64 * 64 * 4);
    float* P        = (float*)alloc((size_t)2 * 512 * 64 * 4);
    float* Weff     = (float*)alloc((size_t)2 * 4096 * 4);
    float* Wpos     = (float*)alloc((size_t)4096 * 4);
    u16*   pbuf     = (u16*)alloc((size_t)2 * 65536 * 64 * 2);
    u16*   tbuf     = (u16*)alloc((size_t)2 * 65536 * 64 * 2);

    hipLaunchKernelGGL(k_convert, dim3(16707), dim3(256), 0, stream,
                       (const u32*)d_in[0], (const u32*)d_in[1], (const u32*)d_in[2],
                       (const u32*)d_in[3], (const u32*)d_in[4], (const u32*)d_in[5],
                       (const u32*)d_in[6], (const u32*)d_in[7], (const u32*)d_in[8],
                       (const u32*)d_in[9], (const u32*)d_in[10], (u32*)cb);

    hipLaunchKernelGGL(k_pool_gram,   dim3(256),  dim3(256), 0, stream, xb, partials);
    hipLaunchKernelGGL(k_gram_reduce, dim3(32),   dim3(256), 0, stream, partials, G);
    hipLaunchKernelGGL(k_gwqk,        dim3(512),  dim3(256), 0, stream, G, wqb, wkb, T, U);
    hipLaunchKernelGGL(k_norms,       dim3(8),    dim3(256), 0, stream, wqb, wkb, T, U, nq, nk);
    hipLaunchKernelGGL(k_attn,        dim3(256),  dim3(256), 0, stream, wkb, T, nq, nk, rsb, attn);
    hipLaunchKernelGGL(k_pmat,        dim3(256),  dim3(256), 0, stream, attn, wpb, P);
    hipLaunchKernelGGL(k_weff,        dim3(48),   dim3(256), 0, stream, wvb, P, wcb, Weff, Wpos);
    hipLaunchKernelGGL(k_pmain,       dim3(2048), dim3(256), 0, stream, xb, Wpos, bcb, pbuf);
    hipLaunchKernelGGL(k_conv1,       dim3(4096), dim3(256), 0, stream, pbuf, p1b, tbuf);
    hipLaunchKernelGGL(k_final,       dim3(2048), dim3(256), 0, stream, xb, tbuf, Weff, p2b,
                       bpb, (const u16*)d_in[4], d_out);
}

// Round 3
// 216.624 us; speedup vs baseline: 1.6688x; 1.6688x over previous
//
#include <hip/hip_runtime.h>
#include <math.h>

// Problem dims (hardcoded per reference): B=2, H=256, W=256, C=64,
// heads=8, dh=64, hd=512, dim_out=64, n=65536/batch.
// Inputs are fp32 (proven: round-1 bf16 reinterpretation NaN'd, round-2
// convert path passed). Output fp32. Tag machinery kept as cheap insurance.
//
// Algebra: attn[b,h,i,j] = (Wk_i^T G[b] Wq_j)/(||k_i|| ||q_j||)*rescale[h],
// G[b] = Xd^T Xd (64x64 Gram of 2x2-avg-pooled input).
//   out = x @ W_eff[b] + bproj + dwconv2(gelu(dwconv1(x @ W_pos + bc1d)))
// with W_eff[b] = Wv @ blockdiag_h(attn_h^T) @ Wproj, W_pos = Wv @ Wc1d.

typedef unsigned short u16;
typedef unsigned int u32;
typedef __attribute__((ext_vector_type(8))) short short8;
typedef __attribute__((ext_vector_type(4))) float f32x4;

__device__ __forceinline__ float bf2f(u16 h) {
    return __uint_as_float(((u32)h) << 16);
}
__device__ __forceinline__ u16 f2bf(float f) {
    u32 u = __float_as_uint(f);
    u32 r = (u + 0x7fffu + ((u >> 16) & 1u)) >> 16;
    return (u16)r;
}
__device__ __forceinline__ void unpack8(uint4 v, float* f) {
    u32 a[4] = {v.x, v.y, v.z, v.w};
#pragma unroll
    for (int i = 0; i < 4; ++i) {
        f[2 * i]     = __uint_as_float(a[i] << 16);
        f[2 * i + 1] = __uint_as_float(a[i] & 0xffff0000u);
    }
}
__device__ __forceinline__ float gelu_exact(float v) {
    return 0.5f * v * (1.f + erff(v * 0.70710678118654752f));
}

// ---------------------------------------------------------------------------
// K0: canonicalize all inputs to bf16 (tag-branched; fp32 path is the real one)
__global__ __launch_bounds__(256) void k_convert(
    const u32* __restrict__ x,  const u32* __restrict__ wq, const u32* __restrict__ wk,
    const u32* __restrict__ wv, const u32* __restrict__ rs, const u32* __restrict__ wp,
    const u32* __restrict__ bp, const u32* __restrict__ wc, const u32* __restrict__ bc,
    const u32* __restrict__ p1, const u32* __restrict__ p2, u32* __restrict__ dst) {
    u32 pid = blockIdx.x * 256 + threadIdx.x;
    if (pid >= 4276868u) return;
    const u32* src; u32 p;
    if      (pid < 4194304u) { src = x;  p = pid; }
    else if (pid < 4210688u) { src = wq; p = pid - 4194304u; }
    else if (pid < 4227072u) { src = wk; p = pid - 4210688u; }
    else if (pid < 4243456u) { src = wv; p = pid - 4227072u; }
    else if (pid < 4243460u) { src = rs; p = pid - 4243456u; }
    else if (pid < 4259844u) { src = wp; p = pid - 4243460u; }
    else if (pid < 4259876u) { src = bp; p = pid - 4259844u; }
    else if (pid < 4276260u) { src = wc; p = pid - 4259876u; }
    else if (pid < 4276292u) { src = bc; p = pid - 4276260u; }
    else if (pid < 4276580u) { src = p1; p = pid - 4276292u; }
    else                     { src = p2; p = pid - 4276580u; }

    u16 tag = ((const u16*)rs)[0];            // 0x3F80 => already bf16
    if (tag == 0x3F80u) {
        dst[pid] = src[p];
    } else {
        const float* sf = (const float*)src;
        dst[pid] = (u32)f2bf(sf[2 * p]) | ((u32)f2bf(sf[2 * p + 1]) << 16);
    }
}

// ---------------------------------------------------------------------------
// K1: fused 2x2 avg-pool + Gram partials (unchanged, verified)
__global__ __launch_bounds__(256) void k_pool_gram(const u16* __restrict__ x,
                                                   float* __restrict__ partials) {
    int blk = blockIdx.x;
    int b   = blk >> 7;
    int py  = blk & 127;
    int t   = threadIdx.x;
    int g   = t >> 6;
    int ch  = t & 63;
    int r0  = (t >> 4) << 2;
    int c0  = (t & 15) << 2;

    __shared__ float xv[4][64];
    float acc[4][4] = {{0.f}};
    const size_t rowbase = ((size_t)(b * 256 + 2 * py)) * 256 * 64;

    for (int tg = 0; tg < 32; ++tg) {
        int px = tg * 4 + g;
        size_t base = rowbase + (size_t)(2 * px) * 64 + ch;
        float v0 = bf2f(x[base]);
        float v1 = bf2f(x[base + 64]);
        float v2 = bf2f(x[base + 256 * 64]);
        float v3 = bf2f(x[base + 256 * 64 + 64]);
        __syncthreads();
        xv[g][ch] = 0.25f * (v0 + v1 + v2 + v3);
        __syncthreads();
#pragma unroll
        for (int gl = 0; gl < 4; ++gl) {
            float a0 = xv[gl][r0], a1 = xv[gl][r0 + 1], a2 = xv[gl][r0 + 2], a3 = xv[gl][r0 + 3];
            float b0 = xv[gl][c0], b1 = xv[gl][c0 + 1], b2 = xv[gl][c0 + 2], b3 = xv[gl][c0 + 3];
            acc[0][0] += a0 * b0; acc[0][1] += a0 * b1; acc[0][2] += a0 * b2; acc[0][3] += a0 * b3;
            acc[1][0] += a1 * b0; acc[1][1] += a1 * b1; acc[1][2] += a1 * b2; acc[1][3] += a1 * b3;
            acc[2][0] += a2 * b0; acc[2][1] += a2 * b1; acc[2][2] += a2 * b2; acc[2][3] += a2 * b3;
            acc[3][0] += a3 * b0; acc[3][1] += a3 * b1; acc[3][2] += a3 * b2; acc[3][3] += a3 * b3;
        }
    }
    float* out = partials + (size_t)blk * 4096;
#pragma unroll
    for (int i = 0; i < 4; ++i)
#pragma unroll
        for (int j = 0; j < 4; ++j)
            out[(r0 + i) * 64 + (c0 + j)] = acc[i][j];
}

// K2: reduce partials -> G[2][64][64]
__global__ __launch_bounds__(256) void k_gram_reduce(const float* __restrict__ partials,
                                                     float* __restrict__ G) {
    int gid = blockIdx.x * 256 + threadIdx.x;
    int b = gid >> 12;
    int e = gid & 4095;
    float s = 0.f;
    for (int p = 0; p < 128; ++p)
        s += partials[((size_t)(b * 128 + p)) * 4096 + e];
    G[b * 4096 + e] = s;
}

// K3: T = G @ Wq, U = G @ Wk
__global__ __launch_bounds__(256) void k_gwqk(const float* __restrict__ G,
                                              const u16* __restrict__ Wq,
                                              const u16* __restrict__ Wk,
                                              float* __restrict__ T,
                                              float* __restrict__ U) {
    int gid = blockIdx.x * 256 + threadIdx.x;
    int j   = gid & 511;
    int c   = (gid >> 9) & 63;
    int b   = (gid >> 15) & 1;
    int sel = gid >> 16;
    const u16* W = sel ? Wk : Wq;
    float s = 0.f;
    const float* Grow = G + b * 4096 + c * 64;
    for (int k = 0; k < 64; ++k)
        s += Grow[k] * bf2f(W[k * 512 + j]);
    float* D = sel ? U : T;
    D[((size_t)(b * 64 + c)) * 512 + j] = s;
}

// K4: column norms
__global__ __launch_bounds__(256) void k_norms(const u16* __restrict__ Wq,
                                               const u16* __restrict__ Wk,
                                               const float* __restrict__ T,
                                               const float* __restrict__ U,
                                               float* __restrict__ nq,
                                               float* __restrict__ nk) {
    int gid = blockIdx.x * 256 + threadIdx.x;
    int j   = gid & 511;
    int b   = (gid >> 9) & 1;
    int sel = gid >> 10;
    const u16* W   = sel ? Wk : Wq;
    const float* D = sel ? U : T;
    float s = 0.f;
    for (int c = 0; c < 64; ++c)
        s += bf2f(W[c * 512 + j]) * D[((size_t)(b * 64 + c)) * 512 + j];
    float n = fmaxf(sqrtf(fmaxf(s, 0.f)), 1e-12f);
    (sel ? nk : nq)[b * 512 + j] = n;
}

// K5: logits + softmax
__global__ __launch_bounds__(256) void k_attn(const u16* __restrict__ Wk,
                                              const float* __restrict__ T,
                                              const float* __restrict__ nq,
                                              const float* __restrict__ nk,
                                              const u16* __restrict__ rescale,
                                              float* __restrict__ attn) {
    int t = threadIdx.x;
    int w = t >> 6;
    int j = t & 63;
    int r = blockIdx.x * 4 + w;
    int b = r >> 9;
    int h = (r >> 6) & 7;
    int i = r & 63;

    float s = 0.f;
    for (int c = 0; c < 64; ++c)
        s += bf2f(Wk[c * 512 + h * 64 + i]) * T[((size_t)(b * 64 + c)) * 512 + h * 64 + j];
    float logit = s * bf2f(rescale[h]) / (nk[b * 512 + h * 64 + i] * nq[b * 512 + h * 64 + j]);

    float m = logit;
#pragma unroll
    for (int d = 32; d >= 1; d >>= 1) m = fmaxf(m, __shfl_xor(m, d, 64));
    float e = __expf(logit - m);
    float ssum = e;
#pragma unroll
    for (int d = 32; d >= 1; d >>= 1) ssum += __shfl_xor(ssum, d, 64);
    attn[((size_t)((b * 8 + h) * 64 + i)) * 64 + j] = e / ssum;
}

// K6: P = blockdiag(attn^T) @ Wproj
__global__ __launch_bounds__(256) void k_pmat(const float* __restrict__ attn,
                                              const u16* __restrict__ Wproj,
                                              float* __restrict__ P) {
    int gid = blockIdx.x * 256 + threadIdx.x;
    int o  = gid & 63;
    int tt = (gid >> 6) & 511;
    int b  = gid >> 15;
    int h  = tt >> 6;
    int j  = tt & 63;
    float s = 0.f;
    for (int i = 0; i < 64; ++i)
        s += attn[((size_t)((b * 8 + h) * 64 + i)) * 64 + j] * bf2f(Wproj[(h * 64 + i) * 64 + o]);
    P[gid] = s;
}

// K7: W_eff[b] = Wv @ P[b], W_pos = Wv @ Wc1d
__global__ __launch_bounds__(256) void k_weff(const u16* __restrict__ Wv,
                                              const float* __restrict__ P,
                                              const u16* __restrict__ Wc1d,
                                              float* __restrict__ Weff,
                                              float* __restrict__ Wpos) {
    int gid = blockIdx.x * 256 + threadIdx.x;
    if (gid < 8192) {
        int o = gid & 63;
        int c = (gid >> 6) & 63;
        int b = gid >> 12;
        float s = 0.f;
        for (int t = 0; t < 512; ++t)
            s += bf2f(Wv[c * 512 + t]) * P[(size_t)b * 32768 + t * 64 + o];
        Weff[b * 4096 + c * 64 + o] = s;
    } else if (gid < 12288) {
        int g2 = gid - 8192;
        int o = g2 & 63;
        int c = g2 >> 6;
        float s = 0.f;
        for (int t = 0; t < 512; ++t)
            s += bf2f(Wv[c * 512 + t]) * bf2f(Wc1d[t * 64 + o]);
        Wpos[c * 64 + o] = s;
    }
}

// ---------------------------------------------------------------------------
// K8: pbuf = xb @ Wpos + bc1d via MFMA 16x16x32 bf16. 512 blocks, 256 px each.
// A-frag: A[m=lane&15][k=quad*8+j] from xb; B-frag symmetric (W^T loaded
// A-style, per m97 gemm_bt); C/D: col=lane&15, row=quad*4+reg (m89).
__global__ __launch_bounds__(256) void k_pmain(const u16* __restrict__ xb,
                                               const float* __restrict__ Wpos,
                                               const u16* __restrict__ bc1d,
                                               u16* __restrict__ pbuf) {
    int t = threadIdx.x;
    int lane = t & 63, wv = t >> 6;
    int col = lane & 15, quad = lane >> 4;

    short8 bf[2][4];
#pragma unroll
    for (int kh = 0; kh < 2; ++kh)
#pragma unroll
        for (int nt = 0; nt < 4; ++nt) {
            short8 v;
#pragma unroll
            for (int j = 0; j < 8; ++j)
                v[j] = (short)f2bf(Wpos[(kh * 32 + quad * 8 + j) * 64 + nt * 16 + col]);
            bf[kh][nt] = v;
        }
    float bias[4];
#pragma unroll
    for (int nt = 0; nt < 4; ++nt) bias[nt] = bf2f(bc1d[nt * 16 + col]);

    size_t base = (size_t)blockIdx.x * 256 + wv * 64;
#pragma unroll
    for (int g = 0; g < 4; ++g) {
        size_t P0 = base + g * 16;
        const short8* ap = (const short8*)(xb + (P0 + col) * 64);
        short8 a0 = ap[quad];
        short8 a1 = ap[4 + quad];
#pragma unroll
        for (int nt = 0; nt < 4; ++nt) {
            f32x4 acc = {0.f, 0.f, 0.f, 0.f};
            acc = __builtin_amdgcn_mfma_f32_16x16x32_bf16(a0, bf[0][nt], acc, 0, 0, 0);
            acc = __builtin_amdgcn_mfma_f32_16x16x32_bf16(a1, bf[1][nt], acc, 0, 0, 0);
#pragma unroll
            for (int r = 0; r < 4; ++r) {
                size_t pix = P0 + quad * 4 + r;
                pbuf[pix * 64 + nt * 16 + col] = f2bf(acc[r] + bias[nt]);
            }
        }
    }
}

// ---------------------------------------------------------------------------
// K9: tbuf = gelu(dwconv3x3(pbuf, Wpe1)). 2D tiles 32x4, halo 34x6 in LDS.
// LDS pixel stride = 72 u16 (144 B): b128 accesses spread uniformly (8 dw/bank).
__global__ __launch_bounds__(256) void k_conv1(const u16* __restrict__ p,
                                               const u16* __restrict__ wpe1,
                                               u16* __restrict__ tbuf) {
    __shared__ u16 sm[204 * 72];
    int t = threadIdx.x;
    int blk = blockIdx.x;            // b*512 + ty*8 + tx
    int b  = blk >> 9;
    int ty = (blk >> 3) & 63;
    int tx = blk & 7;
    int gy0 = ty * 4, gx0 = tx * 32;

    for (int i = t; i < 1632; i += 256) {
        int px = i >> 3, ch = i & 7;
        int hy = px / 34, hx = px - hy * 34;
        int gy = gy0 + hy - 1, gx = gx0 + hx - 1;
        uint4 v = make_uint4(0, 0, 0, 0);
        if ((unsigned)gy < 256u && (unsigned)gx < 256u)
            v = *(const uint4*)(p + ((size_t)((b << 16) + (gy << 8) + gx)) * 64 + ch * 8);
        *(uint4*)(&sm[px * 72 + ch * 8]) = v;
    }
    int oct = t & 7;
    float w[8][9];
#pragma unroll
    for (int j = 0; j < 8; ++j)
#pragma unroll
        for (int k = 0; k < 9; ++k) w[j][k] = bf2f(wpe1[(oct * 8 + j) * 9 + k]);
    __syncthreads();

#pragma unroll
    for (int s = 0; s < 4; ++s) {
        int lp = (t >> 3) + s * 32;
        int ly = lp >> 5, lx = lp & 31;
        float acc[8] = {0.f, 0.f, 0.f, 0.f, 0.f, 0.f, 0.f, 0.f};
#pragma unroll
        for (int dy = 0; dy < 3; ++dy)
#pragma unroll
            for (int dx = 0; dx < 3; ++dx) {
                int hp = (ly + dy) * 34 + lx + dx;
                uint4 v = *(const uint4*)(&sm[hp * 72 + oct * 8]);
                float f[8];
                unpack8(v, f);
                int tap = dy * 3 + dx;
#pragma unroll
                for (int j = 0; j < 8; ++j) acc[j] += f[j] * w[j][tap];
            }
        u32 pk[4];
#pragma unroll
        for (int q = 0; q < 4; ++q) {
            float v0 = gelu_exact(acc[2 * q]);
            float v1 = gelu_exact(acc[2 * q + 1]);
            pk[q] = (u32)f2bf(v0) | ((u32)f2bf(v1) << 16);
        }
        size_t gpix = (size_t)(b << 16) + ((size_t)(gy0 + ly) << 8) + gx0 + lx;
        *(uint4*)(tbuf + gpix * 64 + oct * 8) = make_uint4(pk[0], pk[1], pk[2], pk[3]);
    }
}

// ---------------------------------------------------------------------------
// K10: out = xb @ Weff[b] + bproj + dwconv3x3(tbuf, Wpe2). Tiles 32x4.
// conv2 per-thread (oct of 8 ch) -> bf16 LDS staging; matvec via MFMA;
// epilogue combines and stores fp32 in 64-B lane-contiguous chunks.
__global__ __launch_bounds__(256) void k_final(const u16* __restrict__ xb,
                                               const u16* __restrict__ tbuf,
                                               const float* __restrict__ Weff,
                                               const u16* __restrict__ wpe2,
                                               const u16* __restrict__ bproj,
                                               const u16* __restrict__ rs_raw,
                                               void* __restrict__ outv) {
    __shared__ u16 sm[204 * 72];
    __shared__ u16 cbuf[128 * 72];
    int t = threadIdx.x;
    int blk = blockIdx.x;
    int b  = blk >> 9;
    int ty = (blk >> 3) & 63;
    int tx = blk & 7;
    int gy0 = ty * 4, gx0 = tx * 32;

    for (int i = t; i < 1632; i += 256) {
        int px = i >> 3, ch = i & 7;
        int hy = px / 34, hx = px - hy * 34;
        int gy = gy0 + hy - 1, gx = gx0 + hx - 1;
        uint4 v = make_uint4(0, 0, 0, 0);
        if ((unsigned)gy < 256u && (unsigned)gx < 256u)
            v = *(const uint4*)(tbuf + ((size_t)((b << 16) + (gy << 8) + gx)) * 64 + ch * 8);
        *(uint4*)(&sm[px * 72 + ch * 8]) = v;
    }
    int oct = t & 7;
    {
        float w[8][9];
#pragma unroll
        for (int j = 0; j < 8; ++j)
#pragma unroll
            for (int k = 0; k < 9; ++k) w[j][k] = bf2f(wpe2[(oct * 8 + j) * 9 + k]);
        __syncthreads();
#pragma unroll
        for (int s = 0; s < 4; ++s) {
            int lp = (t >> 3) + s * 32;
            int ly = lp >> 5, lx = lp & 31;
            float acc[8] = {0.f, 0.f, 0.f, 0.f, 0.f, 0.f, 0.f, 0.f};
#pragma unroll
            for (int dy = 0; dy < 3; ++dy)
#pragma unroll
                for (int dx = 0; dx < 3; ++dx) {
                    int hp = (ly + dy) * 34 + lx + dx;
                    uint4 v = *(const uint4*)(&sm[hp * 72 + oct * 8]);
                    float f[8];
                    unpack8(v, f);
                    int tap = dy * 3 + dx;
#pragma unroll
                    for (int j = 0; j < 8; ++j) acc[j] += f[j] * w[j][tap];
                }
            u32 pk[4];
#pragma unroll
            for (int q = 0; q < 4; ++q)
                pk[q] = (u32)f2bf(acc[2 * q]) | ((u32)f2bf(acc[2 * q + 1]) << 16);
            *(uint4*)(&cbuf[lp * 72 + oct * 8]) = make_uint4(pk[0], pk[1], pk[2], pk[3]);
        }
    }
    __syncthreads();

    // MFMA matvec + epilogue
    int lane = t & 63, wv = t >> 6;
    int col = lane & 15, quad = lane >> 4;
    const float* W = Weff + b * 4096;
    short8 bf[2][4];
#pragma unroll
    for (int kh = 0; kh < 2; ++kh)
#pragma unroll
        for (int nt = 0; nt < 4; ++nt) {
            short8 v;
#pragma unroll
            for (int j = 0; j < 8; ++j)
                v[j] = (short)f2bf(W[(kh * 32 + quad * 8 + j) * 64 + nt * 16 + col]);
            bf[kh][nt] = v;
        }
    float bias[4];
#pragma unroll
    for (int nt = 0; nt < 4; ++nt) bias[nt] = bf2f(bproj[nt * 16 + col]);

    u16 tag = rs_raw[0];
#pragma unroll
    for (int g = 0; g < 2; ++g) {
        int grp = wv * 2 + g;               // 0..7 over 128 px
        int ly = grp >> 1;
        int lxb = (grp & 1) * 16;
        size_t rowpix = (size_t)(b << 16) + ((size_t)(gy0 + ly) << 8) + gx0;
        const short8* ap = (const short8*)(xb + (rowpix + lxb + col) * 64);
        short8 a0 = ap[quad];
        short8 a1 = ap[4 + quad];
#pragma unroll
        for (int nt = 0; nt < 4; ++nt) {
            f32x4 acc = {0.f, 0.f, 0.f, 0.f};
            acc = __builtin_amdgcn_mfma_f32_16x16x32_bf16(a0, bf[0][nt], acc, 0, 0, 0);
            acc = __builtin_amdgcn_mfma_f32_16x16x32_bf16(a1, bf[1][nt], acc, 0, 0, 0);
#pragma unroll
            for (int r = 0; r < 4; ++r) {
                int lpx = lxb + quad * 4 + r;
                int lp = ly * 32 + lpx;
                float conv = bf2f(cbuf[lp * 72 + nt * 16 + col]);
                float res = acc[r] + conv + bias[nt];
                size_t idx = (rowpix + lpx) * 64 + nt * 16 + col;
                if (tag == 0x3F80u) ((u16*)outv)[idx] = f2bf(res);
                else                ((float*)outv)[idx] = res;
            }
        }
    }
}

// ---------------------------------------------------------------------------
extern "C" void kernel_launch(void* const* d_in, const int* in_sizes, int n_in,
                              void* d_out, int out_size, void* d_ws, size_t ws_size,
                              hipStream_t stream) {
    char* w = (char*)d_ws;
    size_t off = 0;
    auto alloc = [&](size_t bytes) -> void* {
        void* p = w + off;
        off += (bytes + 255) & ~(size_t)255;
        return p;
    };
    u16* cb = (u16*)alloc((size_t)8553736 * 2);
    u16* xb  = cb;
    u16* wqb = cb + 8388608;
    u16* wkb = wqb + 32768;
    u16* wvb = wkb + 32768;
    u16* rsb = wvb + 32768;
    u16* wpb = rsb + 8;
    u16* bpb = wpb + 32768;
    u16* wcb = bpb + 64;
    u16* bcb = wcb + 32768;
    u16* p1b = bcb + 64;
    u16* p2b = p1b + 576;

    float* partials = (float*)alloc((size_t)2 * 128 * 4096 * 4);
    float* G        = (float*)alloc((size_t)2 * 4096 * 4);
    float* T        = (float*)alloc((size_t)2 * 64 * 512 * 4);
    float* U        = (float*)alloc((size_t)2 * 64 * 512 * 4);
    float* nq       = (float*)alloc((size_t)2 * 512 * 4);
    float* nk       = (float*)alloc((size_t)2 * 512 * 4);
    float* attn     = (float*)alloc((size_t)2 * 8 * 64 * 64 * 4);
    float* P        = (float*)alloc((size_t)2 * 512 * 64 * 4);
    float* Weff     = (float*)alloc((size_t)2 * 4096 * 4);
    float* Wpos     = (float*)alloc((size_t)4096 * 4);
    u16*   pbuf     = (u16*)alloc((size_t)2 * 65536 * 64 * 2);
    u16*   tbuf     = (u16*)alloc((size_t)2 * 65536 * 64 * 2);

    hipLaunchKernelGGL(k_convert, dim3(16707), dim3(256), 0, stream,
                       (const u32*)d_in[0], (const u32*)d_in[1], (const u32*)d_in[2],
                       (const u32*)d_in[3], (const u32*)d_in[4], (const u32*)d_in[5],
                       (const u32*)d_in[6], (const u32*)d_in[7], (const u32*)d_in[8],
                       (const u32*)d_in[9], (const u32*)d_in[10], (u32*)cb);

    hipLaunchKernelGGL(k_pool_gram,   dim3(256),  dim3(256), 0, stream, xb, partials);
    hipLaunchKernelGGL(k_gram_reduce, dim3(32),   dim3(256), 0, stream, partials, G);
    hipLaunchKernelGGL(k_gwqk,        dim3(512),  dim3(256), 0, stream, G, wqb, wkb, T, U);
    hipLaunchKernelGGL(k_norms,       dim3(8),    dim3(256), 0, stream, wqb, wkb, T, U, nq, nk);
    hipLaunchKernelGGL(k_attn,        dim3(256),  dim3(256), 0, stream, wkb, T, nq, nk, rsb, attn);
    hipLaunchKernelGGL(k_pmat,        dim3(256),  dim3(256), 0, stream, attn, wpb, P);
    hipLaunchKernelGGL(k_weff,        dim3(48),   dim3(256), 0, stream, wvb, P, wcb, Weff, Wpos);
    hipLaunchKernelGGL(k_pmain,       dim3(512),  dim3(256), 0, stream, xb, Wpos, bcb, pbuf);
    hipLaunchKernelGGL(k_conv1,       dim3(1024), dim3(256), 0, stream, pbuf, p1b, tbuf);
    hipLaunchKernelGGL(k_final,       dim3(1024), dim3(256), 0, stream, xb, tbuf, Weff, p2b,
                       bpb, (const u16*)d_in[4], d_out);
}

// Round 4
// 213.381 us; speedup vs baseline: 1.6942x; 1.0152x over previous
//
#include <hip/hip_runtime.h>
#include <math.h>

// Dims: B=2, H=256, W=256, C=64, heads=8, dh=64, hd=512, dim_out=64.
// Inputs fp32, output fp32 (proven rounds 1-2). Internally bf16 + MFMA.
//
// Algebra: attn[b,h,i,j] = (Wk_i^T G[b] Wq_j)/(||k_i|| ||q_j||)*rescale[h],
// G[b] = Xd^T Xd (64x64 Gram of 2x2-avg-pooled input).
//   out = x @ W_eff[b] + bproj + dwconv2(gelu(dwconv1(x @ W_pos + bc1d)))
// with W_eff[b] = Wv @ blockdiag_h(attn_h^T) @ Wproj, W_pos = Wv @ Wc1d.

typedef unsigned short u16;
typedef unsigned int u32;
typedef __attribute__((ext_vector_type(8))) short short8;
typedef __attribute__((ext_vector_type(4))) float f32x4;

__device__ __forceinline__ float bf2f(u16 h) {
    return __uint_as_float(((u32)h) << 16);
}
__device__ __forceinline__ u16 f2bf(float f) {
    u32 u = __float_as_uint(f);
    u32 r = (u + 0x7fffu + ((u >> 16) & 1u)) >> 16;
    return (u16)r;
}
__device__ __forceinline__ void unpack8(uint4 v, float* f) {
    u32 a[4] = {v.x, v.y, v.z, v.w};
#pragma unroll
    for (int i = 0; i < 4; ++i) {
        f[2 * i]     = __uint_as_float(a[i] << 16);
        f[2 * i + 1] = __uint_as_float(a[i] & 0xffff0000u);
    }
}
__device__ __forceinline__ float gelu_exact(float v) {
    return 0.5f * v * (1.f + erff(v * 0.70710678118654752f));
}

// ---------------------------------------------------------------------------
// K0: convert WEIGHTS fp32 -> bf16 (x handled by k_pool_gram). 82564 pairs.
__global__ __launch_bounds__(256) void k_convert(
    const float* __restrict__ wq, const float* __restrict__ wk,
    const float* __restrict__ wv, const float* __restrict__ rs,
    const float* __restrict__ wp, const float* __restrict__ bp,
    const float* __restrict__ wc, const float* __restrict__ bc,
    const float* __restrict__ p1, const float* __restrict__ p2,
    u32* __restrict__ dst) {
    u32 pid = blockIdx.x * 256 + threadIdx.x;
    if (pid >= 82564u) return;
    const float* src; u32 p;
    if      (pid < 16384u) { src = wq; p = pid; }
    else if (pid < 32768u) { src = wk; p = pid - 16384u; }
    else if (pid < 49152u) { src = wv; p = pid - 32768u; }
    else if (pid < 49156u) { src = rs; p = pid - 49152u; }
    else if (pid < 65540u) { src = wp; p = pid - 49156u; }
    else if (pid < 65572u) { src = bp; p = pid - 65540u; }
    else if (pid < 81956u) { src = wc; p = pid - 65572u; }
    else if (pid < 81988u) { src = bc; p = pid - 81956u; }
    else if (pid < 82276u) { src = p1; p = pid - 81988u; }
    else                   { src = p2; p = pid - 82276u; }
    dst[pid] = (u32)f2bf(src[2 * p]) | ((u32)f2bf(src[2 * p + 1]) << 16);
}

// ---------------------------------------------------------------------------
// K1: fp32 x -> (xb bf16, pooled Gram partials). 256 blocks.
__global__ __launch_bounds__(256) void k_pool_gram(const float* __restrict__ x,
                                                   u16* __restrict__ xb,
                                                   float* __restrict__ partials) {
    int blk = blockIdx.x;
    int b   = blk >> 7;
    int py  = blk & 127;
    int t   = threadIdx.x;
    int g   = t >> 6;
    int ch  = t & 63;
    int r0  = (t >> 4) << 2;
    int c0  = (t & 15) << 2;

    __shared__ float xv[4][64];
    float acc[4][4] = {{0.f}};
    const size_t rowbase = ((size_t)(b * 256 + 2 * py)) * 256 * 64;

    for (int tg = 0; tg < 32; ++tg) {
        int px = tg * 4 + g;
        size_t base = rowbase + (size_t)(2 * px) * 64 + ch;
        float v0 = x[base];
        float v1 = x[base + 64];
        float v2 = x[base + 256 * 64];
        float v3 = x[base + 256 * 64 + 64];
        xb[base]                = f2bf(v0);
        xb[base + 64]           = f2bf(v1);
        xb[base + 256 * 64]      = f2bf(v2);
        xb[base + 256 * 64 + 64] = f2bf(v3);
        __syncthreads();
        xv[g][ch] = 0.25f * (v0 + v1 + v2 + v3);
        __syncthreads();
#pragma unroll
        for (int gl = 0; gl < 4; ++gl) {
            float a0 = xv[gl][r0], a1 = xv[gl][r0 + 1], a2 = xv[gl][r0 + 2], a3 = xv[gl][r0 + 3];
            float b0 = xv[gl][c0], b1 = xv[gl][c0 + 1], b2 = xv[gl][c0 + 2], b3 = xv[gl][c0 + 3];
            acc[0][0] += a0 * b0; acc[0][1] += a0 * b1; acc[0][2] += a0 * b2; acc[0][3] += a0 * b3;
            acc[1][0] += a1 * b0; acc[1][1] += a1 * b1; acc[1][2] += a1 * b2; acc[1][3] += a1 * b3;
            acc[2][0] += a2 * b0; acc[2][1] += a2 * b1; acc[2][2] += a2 * b2; acc[2][3] += a2 * b3;
            acc[3][0] += a3 * b0; acc[3][1] += a3 * b1; acc[3][2] += a3 * b2; acc[3][3] += a3 * b3;
        }
    }
    float* out = partials + (size_t)blk * 4096;
#pragma unroll
    for (int i = 0; i < 4; ++i)
#pragma unroll
        for (int j = 0; j < 4; ++j)
            out[(r0 + i) * 64 + (c0 + j)] = acc[i][j];
}

// K2: reduce partials -> G[2][64][64]
__global__ __launch_bounds__(256) void k_gram_reduce(const float* __restrict__ partials,
                                                     float* __restrict__ G) {
    int gid = blockIdx.x * 256 + threadIdx.x;
    int b = gid >> 12;
    int e = gid & 4095;
    float s = 0.f;
    for (int p = 0; p < 128; ++p)
        s += partials[((size_t)(b * 128 + p)) * 4096 + e];
    G[b * 4096 + e] = s;
}

// K3: T = G @ Wq, U = G @ Wk
__global__ __launch_bounds__(256) void k_gwqk(const float* __restrict__ G,
                                              const u16* __restrict__ Wq,
                                              const u16* __restrict__ Wk,
                                              float* __restrict__ T,
                                              float* __restrict__ U) {
    int gid = blockIdx.x * 256 + threadIdx.x;
    int j   = gid & 511;
    int c   = (gid >> 9) & 63;
    int b   = (gid >> 15) & 1;
    int sel = gid >> 16;
    const u16* W = sel ? Wk : Wq;
    float s = 0.f;
    const float* Grow = G + b * 4096 + c * 64;
    for (int k = 0; k < 64; ++k)
        s += Grow[k] * bf2f(W[k * 512 + j]);
    float* D = sel ? U : T;
    D[((size_t)(b * 64 + c)) * 512 + j] = s;
}

// K4: column norms
__global__ __launch_bounds__(256) void k_norms(const u16* __restrict__ Wq,
                                               const u16* __restrict__ Wk,
                                               const float* __restrict__ T,
                                               const float* __restrict__ U,
                                               float* __restrict__ nq,
                                               float* __restrict__ nk) {
    int gid = blockIdx.x * 256 + threadIdx.x;
    int j   = gid & 511;
    int b   = (gid >> 9) & 1;
    int sel = gid >> 10;
    const u16* W   = sel ? Wk : Wq;
    const float* D = sel ? U : T;
    float s = 0.f;
    for (int c = 0; c < 64; ++c)
        s += bf2f(W[c * 512 + j]) * D[((size_t)(b * 64 + c)) * 512 + j];
    float n = fmaxf(sqrtf(fmaxf(s, 0.f)), 1e-12f);
    (sel ? nk : nq)[b * 512 + j] = n;
}

// K5: logits + softmax
__global__ __launch_bounds__(256) void k_attn(const u16* __restrict__ Wk,
                                              const float* __restrict__ T,
                                              const float* __restrict__ nq,
                                              const float* __restrict__ nk,
                                              const u16* __restrict__ rescale,
                                              float* __restrict__ attn) {
    int t = threadIdx.x;
    int w = t >> 6;
    int j = t & 63;
    int r = blockIdx.x * 4 + w;
    int b = r >> 9;
    int h = (r >> 6) & 7;
    int i = r & 63;

    float s = 0.f;
    for (int c = 0; c < 64; ++c)
        s += bf2f(Wk[c * 512 + h * 64 + i]) * T[((size_t)(b * 64 + c)) * 512 + h * 64 + j];
    float logit = s * bf2f(rescale[h]) / (nk[b * 512 + h * 64 + i] * nq[b * 512 + h * 64 + j]);

    float m = logit;
#pragma unroll
    for (int d = 32; d >= 1; d >>= 1) m = fmaxf(m, __shfl_xor(m, d, 64));
    float e = __expf(logit - m);
    float ssum = e;
#pragma unroll
    for (int d = 32; d >= 1; d >>= 1) ssum += __shfl_xor(ssum, d, 64);
    attn[((size_t)((b * 8 + h) * 64 + i)) * 64 + j] = e / ssum;
}

// K6: P = blockdiag(attn^T) @ Wproj
__global__ __launch_bounds__(256) void k_pmat(const float* __restrict__ attn,
                                              const u16* __restrict__ Wproj,
                                              float* __restrict__ P) {
    int gid = blockIdx.x * 256 + threadIdx.x;
    int o  = gid & 63;
    int tt = (gid >> 6) & 511;
    int b  = gid >> 15;
    int h  = tt >> 6;
    int j  = tt & 63;
    float s = 0.f;
    for (int i = 0; i < 64; ++i)
        s += attn[((size_t)((b * 8 + h) * 64 + i)) * 64 + j] * bf2f(Wproj[(h * 64 + i) * 64 + o]);
    P[gid] = s;
}

// K7: W_eff[b] = Wv @ P[b], W_pos = Wv @ Wc1d
__global__ __launch_bounds__(256) void k_weff(const u16* __restrict__ Wv,
                                              const float* __restrict__ P,
                                              const u16* __restrict__ Wc1d,
                                              float* __restrict__ Weff,
                                              float* __restrict__ Wpos) {
    int gid = blockIdx.x * 256 + threadIdx.x;
    if (gid < 8192) {
        int o = gid & 63;
        int c = (gid >> 6) & 63;
        int b = gid >> 12;
        float s = 0.f;
        for (int t = 0; t < 512; ++t)
            s += bf2f(Wv[c * 512 + t]) * P[(size_t)b * 32768 + t * 64 + o];
        Weff[b * 4096 + c * 64 + o] = s;
    } else if (gid < 12288) {
        int g2 = gid - 8192;
        int o = g2 & 63;
        int c = g2 >> 6;
        float s = 0.f;
        for (int t = 0; t < 512; ++t)
            s += bf2f(Wv[c * 512 + t]) * bf2f(Wc1d[t * 64 + o]);
        Wpos[c * 64 + o] = s;
    }
}

// ---------------------------------------------------------------------------
// K8: pbuf = xb @ Wpos + bc1d via MFMA, LDS-staged vectorized stores.
// 512 blocks x 256 px. LDS px stride 72 u16 (b128 readout is uniform 8 dw/bank).
__global__ __launch_bounds__(256) void k_pmain(const u16* __restrict__ xb,
                                               const float* __restrict__ Wpos,
                                               const u16* __restrict__ bc1d,
                                               u16* __restrict__ pbuf) {
    __shared__ u16 sm[256 * 72];
    int t = threadIdx.x;
    int lane = t & 63, wv = t >> 6;
    int col = lane & 15, quad = lane >> 4;

    short8 bf[2][4];
#pragma unroll
    for (int kh = 0; kh < 2; ++kh)
#pragma unroll
        for (int nt = 0; nt < 4; ++nt) {
            short8 v;
#pragma unroll
            for (int j = 0; j < 8; ++j)
                v[j] = (short)f2bf(Wpos[(kh * 32 + quad * 8 + j) * 64 + nt * 16 + col]);
            bf[kh][nt] = v;
        }
    float bias[4];
#pragma unroll
    for (int nt = 0; nt < 4; ++nt) bias[nt] = bf2f(bc1d[nt * 16 + col]);

    size_t base = (size_t)blockIdx.x * 256;
#pragma unroll
    for (int g = 0; g < 4; ++g) {
        int P0 = wv * 64 + g * 16;
        const short8* ap = (const short8*)(xb + (base + P0 + col) * 64);
        short8 a0 = ap[quad];
        short8 a1 = ap[4 + quad];
#pragma unroll
        for (int nt = 0; nt < 4; ++nt) {
            f32x4 acc = {0.f, 0.f, 0.f, 0.f};
            acc = __builtin_amdgcn_mfma_f32_16x16x32_bf16(a0, bf[0][nt], acc, 0, 0, 0);
            acc = __builtin_amdgcn_mfma_f32_16x16x32_bf16(a1, bf[1][nt], acc, 0, 0, 0);
#pragma unroll
            for (int r = 0; r < 4; ++r)
                sm[(P0 + quad * 4 + r) * 72 + nt * 16 + col] = f2bf(acc[r] + bias[nt]);
        }
    }
    __syncthreads();
#pragma unroll
    for (int k = 0; k < 8; ++k) {
        int linear = k * 256 + t;
        int px = linear >> 3, oct = linear & 7;
        uint4 v = *(const uint4*)(&sm[px * 72 + oct * 8]);
        *(uint4*)(pbuf + (base + px) * 64 + oct * 8) = v;
    }
}

// ---------------------------------------------------------------------------
// K9: tbuf = gelu(dwconv3x3(pbuf, Wpe1)). 2D tiles 32x4, halo 34x6 in LDS.
__global__ __launch_bounds__(256) void k_conv1(const u16* __restrict__ p,
                                               const u16* __restrict__ wpe1,
                                               u16* __restrict__ tbuf) {
    __shared__ u16 sm[204 * 72];
    int t = threadIdx.x;
    int blk = blockIdx.x;
    int b  = blk >> 9;
    int ty = (blk >> 3) & 63;
    int tx = blk & 7;
    int gy0 = ty * 4, gx0 = tx * 32;

    for (int i = t; i < 1632; i += 256) {
        int px = i >> 3, ch = i & 7;
        int hy = px / 34, hx = px - hy * 34;
        int gy = gy0 + hy - 1, gx = gx0 + hx - 1;
        uint4 v = make_uint4(0, 0, 0, 0);
        if ((unsigned)gy < 256u && (unsigned)gx < 256u)
            v = *(const uint4*)(p + ((size_t)((b << 16) + (gy << 8) + gx)) * 64 + ch * 8);
        *(uint4*)(&sm[px * 72 + ch * 8]) = v;
    }
    int oct = t & 7;
    float w[8][9];
#pragma unroll
    for (int j = 0; j < 8; ++j)
#pragma unroll
        for (int k = 0; k < 9; ++k) w[j][k] = bf2f(wpe1[(oct * 8 + j) * 9 + k]);
    __syncthreads();

#pragma unroll
    for (int s = 0; s < 4; ++s) {
        int lp = (t >> 3) + s * 32;
        int ly = lp >> 5, lx = lp & 31;
        float acc[8] = {0.f, 0.f, 0.f, 0.f, 0.f, 0.f, 0.f, 0.f};
#pragma unroll
        for (int dy = 0; dy < 3; ++dy)
#pragma unroll
            for (int dx = 0; dx < 3; ++dx) {
                int hp = (ly + dy) * 34 + lx + dx;
                uint4 v = *(const uint4*)(&sm[hp * 72 + oct * 8]);
                float f[8];
                unpack8(v, f);
                int tap = dy * 3 + dx;
#pragma unroll
                for (int j = 0; j < 8; ++j) acc[j] += f[j] * w[j][tap];
            }
        u32 pk[4];
#pragma unroll
        for (int q = 0; q < 4; ++q) {
            float v0 = gelu_exact(acc[2 * q]);
            float v1 = gelu_exact(acc[2 * q + 1]);
            pk[q] = (u32)f2bf(v0) | ((u32)f2bf(v1) << 16);
        }
        size_t gpix = (size_t)(b << 16) + ((size_t)(gy0 + ly) << 8) + gx0 + lx;
        *(uint4*)(tbuf + gpix * 64 + oct * 8) = make_uint4(pk[0], pk[1], pk[2], pk[3]);
    }
}

// ---------------------------------------------------------------------------
// K10: out = xb @ Weff[b] + bproj + dwconv3x3(tbuf, Wpe2). Tiles 32x4.
// conv2 -> fp32 stage; MFMA adds into stage; cooperative float4 stores.
__global__ __launch_bounds__(256) void k_final(const u16* __restrict__ xb,
                                               const u16* __restrict__ tbuf,
                                               const float* __restrict__ Weff,
                                               const u16* __restrict__ wpe2,
                                               const u16* __restrict__ bproj,
                                               float* __restrict__ out) {
    __shared__ u16 sm[204 * 72];
    __shared__ float stage[128 * 68];
    int t = threadIdx.x;
    int blk = blockIdx.x;
    int b  = blk >> 9;
    int ty = (blk >> 3) & 63;
    int tx = blk & 7;
    int gy0 = ty * 4, gx0 = tx * 32;

    for (int i = t; i < 1632; i += 256) {
        int px = i >> 3, ch = i & 7;
        int hy = px / 34, hx = px - hy * 34;
        int gy = gy0 + hy - 1, gx = gx0 + hx - 1;
        uint4 v = make_uint4(0, 0, 0, 0);
        if ((unsigned)gy < 256u && (unsigned)gx < 256u)
            v = *(const uint4*)(tbuf + ((size_t)((b << 16) + (gy << 8) + gx)) * 64 + ch * 8);
        *(uint4*)(&sm[px * 72 + ch * 8]) = v;
    }
    int oct = t & 7;
    {
        float w[8][9];
#pragma unroll
        for (int j = 0; j < 8; ++j)
#pragma unroll
            for (int k = 0; k < 9; ++k) w[j][k] = bf2f(wpe2[(oct * 8 + j) * 9 + k]);
        __syncthreads();
#pragma unroll
        for (int s = 0; s < 4; ++s) {
            int lp = (t >> 3) + s * 32;
            int ly = lp >> 5, lx = lp & 31;
            float acc[8] = {0.f, 0.f, 0.f, 0.f, 0.f, 0.f, 0.f, 0.f};
#pragma unroll
            for (int dy = 0; dy < 3; ++dy)
#pragma unroll
                for (int dx = 0; dx < 3; ++dx) {
                    int hp = (ly + dy) * 34 + lx + dx;
                    uint4 v = *(const uint4*)(&sm[hp * 72 + oct * 8]);
                    float f[8];
                    unpack8(v, f);
                    int tap = dy * 3 + dx;
#pragma unroll
                    for (int j = 0; j < 8; ++j) acc[j] += f[j] * w[j][tap];
                }
#pragma unroll
            for (int j = 0; j < 8; ++j)
                stage[lp * 68 + oct * 8 + j] = acc[j];
        }
    }
    __syncthreads();

    // MFMA matvec, add into stage
    int lane = t & 63, wv = t >> 6;
    int col = lane & 15, quad = lane >> 4;
    const float* W = Weff + b * 4096;
    short8 bf[2][4];
#pragma unroll
    for (int kh = 0; kh < 2; ++kh)
#pragma unroll
        for (int nt = 0; nt < 4; ++nt) {
            short8 v;
#pragma unroll
            for (int j = 0; j < 8; ++j)
                v[j] = (short)f2bf(W[(kh * 32 + quad * 8 + j) * 64 + nt * 16 + col]);
            bf[kh][nt] = v;
        }
    float bias[4];
#pragma unroll
    for (int nt = 0; nt < 4; ++nt) bias[nt] = bf2f(bproj[nt * 16 + col]);

#pragma unroll
    for (int g = 0; g < 2; ++g) {
        int grp = wv * 2 + g;               // 0..7 over 128 px
        int ly = grp >> 1;
        int lxb = (grp & 1) * 16;
        size_t rowpix = (size_t)(b << 16) + ((size_t)(gy0 + ly) << 8) + gx0;
        const short8* ap = (const short8*)(xb + (rowpix + lxb + col) * 64);
        short8 a0 = ap[quad];
        short8 a1 = ap[4 + quad];
#pragma unroll
        for (int nt = 0; nt < 4; ++nt) {
            f32x4 acc = {0.f, 0.f, 0.f, 0.f};
            acc = __builtin_amdgcn_mfma_f32_16x16x32_bf16(a0, bf[0][nt], acc, 0, 0, 0);
            acc = __builtin_amdgcn_mfma_f32_16x16x32_bf16(a1, bf[1][nt], acc, 0, 0, 0);
#pragma unroll
            for (int r = 0; r < 4; ++r) {
                int lp = ly * 32 + lxb + quad * 4 + r;
                stage[lp * 68 + nt * 16 + col] += acc[r] + bias[nt];
            }
        }
    }
    __syncthreads();

    // cooperative full-line stores: 128 px x 16 float4 chunks
#pragma unroll
    for (int k = 0; k < 8; ++k) {
        int linear = k * 256 + t;
        int px = linear >> 4, c4 = linear & 15;
        int ly = px >> 5, lx = px & 31;
        float4 v = *(const float4*)(&stage[px * 68 + c4 * 4]);
        size_t gpix = (size_t)(b << 16) + ((size_t)(gy0 + ly) << 8) + gx0 + lx;
        *(float4*)(out + gpix * 64 + c4 * 4) = v;
    }
}

// ---------------------------------------------------------------------------
extern "C" void kernel_launch(void* const* d_in, const int* in_sizes, int n_in,
                              void* d_out, int out_size, void* d_ws, size_t ws_size,
                              hipStream_t stream) {
    const float* x = (const float*)d_in[0];
    float* out = (float*)d_out;

    char* w = (char*)d_ws;
    size_t off = 0;
    auto alloc = [&](size_t bytes) -> void* {
        void* p = w + off;
        off += (bytes + 255) & ~(size_t)255;
        return p;
    };
    u16* xb = (u16*)alloc((size_t)16777216 * 2);
    u16* wb = (u16*)alloc((size_t)165128 * 2);
    u16* wqb = wb;
    u16* wkb = wqb + 32768;
    u16* wvb = wkb + 32768;
    u16* rsb = wvb + 32768;
    u16* wpb = rsb + 8;
    u16* bpb = wpb + 32768;
    u16* wcb = bpb + 64;
    u16* bcb = wcb + 32768;
    u16* p1b = bcb + 64;
    u16* p2b = p1b + 576;

    float* partials = (float*)alloc((size_t)2 * 128 * 4096 * 4);
    float* G        = (float*)alloc((size_t)2 * 4096 * 4);
    float* T        = (float*)alloc((size_t)2 * 64 * 512 * 4);
    float* U        = (float*)alloc((size_t)2 * 64 * 512 * 4);
    float* nq       = (float*)alloc((size_t)2 * 512 * 4);
    float* nk       = (float*)alloc((size_t)2 * 512 * 4);
    float* attn     = (float*)alloc((size_t)2 * 8 * 64 * 64 * 4);
    float* P        = (float*)alloc((size_t)2 * 512 * 64 * 4);
    float* Weff     = (float*)alloc((size_t)2 * 4096 * 4);
    float* Wpos     = (float*)alloc((size_t)4096 * 4);
    u16*   pbuf     = (u16*)alloc((size_t)2 * 65536 * 64 * 2);
    u16*   tbuf     = (u16*)alloc((size_t)2 * 65536 * 64 * 2);

    hipLaunchKernelGGL(k_convert, dim3(323), dim3(256), 0, stream,
                       (const float*)d_in[1], (const float*)d_in[2], (const float*)d_in[3],
                       (const float*)d_in[4], (const float*)d_in[5], (const float*)d_in[6],
                       (const float*)d_in[7], (const float*)d_in[8], (const float*)d_in[9],
                       (const float*)d_in[10], (u32*)wb);

    hipLaunchKernelGGL(k_pool_gram,   dim3(256),  dim3(256), 0, stream, x, xb, partials);
    hipLaunchKernelGGL(k_gram_reduce, dim3(32),   dim3(256), 0, stream, partials, G);
    hipLaunchKernelGGL(k_gwqk,        dim3(512),  dim3(256), 0, stream, G, wqb, wkb, T, U);
    hipLaunchKernelGGL(k_norms,       dim3(8),    dim3(256), 0, stream, wqb, wkb, T, U, nq, nk);
    hipLaunchKernelGGL(k_attn,        dim3(256),  dim3(256), 0, stream, wkb, T, nq, nk, rsb, attn);
    hipLaunchKernelGGL(k_pmat,        dim3(256),  dim3(256), 0, stream, attn, wpb, P);
    hipLaunchKernelGGL(k_weff,        dim3(48),   dim3(256), 0, stream, wvb, P, wcb, Weff, Wpos);
    hipLaunchKernelGGL(k_pmain,       dim3(512),  dim3(256), 0, stream, xb, Wpos, bcb, pbuf);
    hipLaunchKernelGGL(k_conv1,       dim3(1024), dim3(256), 0, stream, pbuf, p1b, tbuf);
    hipLaunchKernelGGL(k_final,       dim3(1024), dim3(256), 0, stream, xb, tbuf, Weff, p2b,
                       bpb, out);
}

// Round 5
// 196.154 us; speedup vs baseline: 1.8430x; 1.0878x over previous
//
#include <hip/hip_runtime.h>
#include <math.h>

// Dims: B=2, H=256, W=256, C=64, heads=8, dh=64, hd=512, dim_out=64.
// Inputs fp32, output fp32 (proven r1/r2). Internals bf16 + MFMA.
//
// attn[b,h,i,j] = (Wk_i^T G[b] Wq_j)/(||k_i|| ||q_j||)*rescale[h],
// G[b] = Xd^T Xd (Gram of 2x2-avg-pooled input).
// out = x@W_eff[b] + bproj + dwconv2(gelu(dwconv1(x@W_pos + bc1d)))
// W_eff[b] = Wv @ blockdiag_h(attn_h^T) @ Wproj,  W_pos = Wv @ Wc1d.
//
// 5 launches: independent stages packed into shared dispatches by blockIdx.

typedef unsigned short u16;
typedef unsigned int u32;
typedef __attribute__((ext_vector_type(8))) short short8;
typedef __attribute__((ext_vector_type(4))) float f32x4;

__device__ __forceinline__ float bf2f(u16 h) { return __uint_as_float(((u32)h) << 16); }
__device__ __forceinline__ u16 f2bf(float f) {
    u32 u = __float_as_uint(f);
    return (u16)((u + 0x7fffu + ((u >> 16) & 1u)) >> 16);
}
__device__ __forceinline__ float rbf(float f) { return bf2f(f2bf(f)); }
__device__ __forceinline__ u32 pk2(float lo, float hi) {
    return (u32)f2bf(lo) | ((u32)f2bf(hi) << 16);
}
__device__ __forceinline__ void unpack8(uint4 v, float* f) {
    u32 a[4] = {v.x, v.y, v.z, v.w};
#pragma unroll
    for (int i = 0; i < 4; ++i) {
        f[2 * i]     = __uint_as_float(a[i] << 16);
        f[2 * i + 1] = __uint_as_float(a[i] & 0xffff0000u);
    }
}
__device__ __forceinline__ float gelu_exact(float v) {
    return 0.5f * v * (1.f + erff(v * 0.70710678118654752f));
}

// ---------------------------------------------------------------------------
// K1: blocks 0..322 weight fp32->bf16; 323..338 Wpos = Wv@Wc1d (bf16-rounded);
//     339..594 pool+Gram partials + xb emit (single-barrier version).
__global__ __launch_bounds__(256) void k_front(
    const float* __restrict__ x,
    const float* __restrict__ wq_f, const float* __restrict__ wk_f,
    const float* __restrict__ wv_f, const float* __restrict__ rs_f,
    const float* __restrict__ wp_f, const float* __restrict__ bp_f,
    const float* __restrict__ wc_f, const float* __restrict__ bc_f,
    const float* __restrict__ p1_f, const float* __restrict__ p2_f,
    u32* __restrict__ wb32, float* __restrict__ Wpos,
    u16* __restrict__ xb, float* __restrict__ partials) {
    __shared__ float xvs[128 * 68];
    int blk = blockIdx.x;
    int t = threadIdx.x;
    if (blk < 323) {
        u32 pid = (u32)blk * 256u + t;
        if (pid < 82564u) {
            const float* src; u32 p;
            if      (pid < 16384u) { src = wq_f; p = pid; }
            else if (pid < 32768u) { src = wk_f; p = pid - 16384u; }
            else if (pid < 49152u) { src = wv_f; p = pid - 32768u; }
            else if (pid < 49156u) { src = rs_f; p = pid - 49152u; }
            else if (pid < 65540u) { src = wp_f; p = pid - 49156u; }
            else if (pid < 65572u) { src = bp_f; p = pid - 65540u; }
            else if (pid < 81956u) { src = wc_f; p = pid - 65572u; }
            else if (pid < 81988u) { src = bc_f; p = pid - 81956u; }
            else if (pid < 82276u) { src = p1_f; p = pid - 81988u; }
            else                   { src = p2_f; p = pid - 82276u; }
            wb32[pid] = (u32)f2bf(src[2 * p]) | ((u32)f2bf(src[2 * p + 1]) << 16);
        }
    } else if (blk < 339) {
        int wpid = (blk - 323) * 256 + t;     // 0..4095
        int o = wpid & 63, c = wpid >> 6;
        float s = 0.f;
        for (int k = 0; k < 512; ++k)
            s += rbf(wv_f[c * 512 + k]) * rbf(wc_f[k * 64 + o]);
        Wpos[c * 64 + o] = s;
    } else {
        int pb = blk - 339;                   // 0..255
        int b = pb >> 7, py = pb & 127;
        const size_t rowbase = (size_t)(b * 256 + 2 * py) * 16384;
#pragma unroll
        for (int i2 = 0; i2 < 8; ++i2) {
            int u = t + 256 * i2;
            int P = u >> 4, cq = u & 15;
            size_t o0 = rowbase + (size_t)(2 * P) * 64 + cq * 4;
            float4 a0 = *(const float4*)(x + o0);
            float4 a1 = *(const float4*)(x + o0 + 64);
            float4 a2 = *(const float4*)(x + o0 + 16384);
            float4 a3 = *(const float4*)(x + o0 + 16384 + 64);
            *(uint2*)(xb + o0)              = make_uint2(pk2(a0.x, a0.y), pk2(a0.z, a0.w));
            *(uint2*)(xb + o0 + 64)         = make_uint2(pk2(a1.x, a1.y), pk2(a1.z, a1.w));
            *(uint2*)(xb + o0 + 16384)      = make_uint2(pk2(a2.x, a2.y), pk2(a2.z, a2.w));
            *(uint2*)(xb + o0 + 16384 + 64) = make_uint2(pk2(a3.x, a3.y), pk2(a3.z, a3.w));
            float4 s;
            s.x = 0.25f * (a0.x + a1.x + a2.x + a3.x);
            s.y = 0.25f * (a0.y + a1.y + a2.y + a3.y);
            s.z = 0.25f * (a0.z + a1.z + a2.z + a3.z);
            s.w = 0.25f * (a0.w + a1.w + a2.w + a3.w);
            *(float4*)(&xvs[P * 68 + cq * 4]) = s;
        }
        __syncthreads();
        int r0 = (t >> 4) << 2, c0 = (t & 15) << 2;
        float acc[4][4] = {{0.f}};
        for (int P = 0; P < 128; ++P) {
            float4 av = *(const float4*)(&xvs[P * 68 + r0]);
            float4 bv = *(const float4*)(&xvs[P * 68 + c0]);
            float ar[4] = {av.x, av.y, av.z, av.w};
            float br[4] = {bv.x, bv.y, bv.z, bv.w};
#pragma unroll
            for (int i = 0; i < 4; ++i)
#pragma unroll
                for (int j = 0; j < 4; ++j)
                    acc[i][j] += ar[i] * br[j];
        }
        float* outp = partials + (size_t)pb * 4096;
#pragma unroll
        for (int i = 0; i < 4; ++i)
            *(float4*)(&outp[(r0 + i) * 64 + c0]) =
                make_float4(acc[i][0], acc[i][1], acc[i][2], acc[i][3]);
    }
}

// ---------------------------------------------------------------------------
// K2: blocks 0..31 Gram reduce (+Weff zero); 32..543 pmain (MFMA matvec).
__global__ __launch_bounds__(256) void k_mid1(
    const float* __restrict__ partials, float* __restrict__ G, float* __restrict__ Weff,
    const u16* __restrict__ xb, const float* __restrict__ Wpos,
    const u16* __restrict__ bc1d, u16* __restrict__ pbuf) {
    __shared__ u16 sm[256 * 72];
    int blk = blockIdx.x;
    int t = threadIdx.x;
    if (blk < 32) {
        int gid = blk * 256 + t;              // 0..8191
        int b = gid >> 12, e = gid & 4095;
        float s = 0.f;
        for (int p = 0; p < 128; ++p)
            s += partials[((size_t)(b * 128 + p)) * 4096 + e];
        G[b * 4096 + e] = s;
        Weff[gid] = 0.f;
        return;
    }
    int pb = blk - 32;                        // 0..511
    int lane = t & 63, wv = t >> 6;
    int col = lane & 15, quad = lane >> 4;

    short8 bf[2][4];
#pragma unroll
    for (int kh = 0; kh < 2; ++kh)
#pragma unroll
        for (int nt = 0; nt < 4; ++nt) {
            short8 v;
#pragma unroll
            for (int j = 0; j < 8; ++j)
                v[j] = (short)f2bf(Wpos[(kh * 32 + quad * 8 + j) * 64 + nt * 16 + col]);
            bf[kh][nt] = v;
        }
    float bias[4];
#pragma unroll
    for (int nt = 0; nt < 4; ++nt) bias[nt] = bf2f(bc1d[nt * 16 + col]);

    size_t base = (size_t)pb * 256;
#pragma unroll
    for (int g = 0; g < 4; ++g) {
        int P0 = wv * 64 + g * 16;
        const short8* ap = (const short8*)(xb + (base + P0 + col) * 64);
        short8 a0 = ap[quad];
        short8 a1 = ap[4 + quad];
#pragma unroll
        for (int nt = 0; nt < 4; ++nt) {
            f32x4 acc = {0.f, 0.f, 0.f, 0.f};
            acc = __builtin_amdgcn_mfma_f32_16x16x32_bf16(a0, bf[0][nt], acc, 0, 0, 0);
            acc = __builtin_amdgcn_mfma_f32_16x16x32_bf16(a1, bf[1][nt], acc, 0, 0, 0);
#pragma unroll
            for (int r = 0; r < 4; ++r)
                sm[(P0 + quad * 4 + r) * 72 + nt * 16 + col] = f2bf(acc[r] + bias[nt]);
        }
    }
    __syncthreads();
#pragma unroll
    for (int k = 0; k < 8; ++k) {
        int linear = k * 256 + t;
        int px = linear >> 3, oct = linear & 7;
        uint4 v = *(const uint4*)(&sm[px * 72 + oct * 8]);
        *(uint4*)(pbuf + (base + px) * 64 + oct * 8) = v;
    }
}

// ---------------------------------------------------------------------------
// K3: fused T=G@Wq (and G@Wk for norms only) + column norms. 32 blocks:
// (b, sel, jg). U never written to HBM; norm uses the k==c row of W reloaded.
__global__ __launch_bounds__(256) void k_gwqk_norms(
    const float* __restrict__ G, const u16* __restrict__ wqb, const u16* __restrict__ wkb,
    float* __restrict__ T, float* __restrict__ nq, float* __restrict__ nk) {
    __shared__ __align__(16) float Gs[64 * 68];
    __shared__ __align__(16) float Ps[64 * 68];
    int blk = blockIdx.x, t = threadIdx.x;
    int b = blk >> 4, sel = (blk >> 3) & 1, jg = blk & 7;
    const u16* Wsel = sel ? wkb : wqb;
    {
        int base = t * 16;
        int row = base >> 6, col = base & 63;
#pragma unroll
        for (int q = 0; q < 4; ++q)
            *(float4*)(&Gs[row * 68 + col + 4 * q]) =
                *(const float4*)(&G[b * 4096 + base + 4 * q]);
    }
    __syncthreads();
    int c = t >> 2, jq = t & 3;
    int jbase = jg * 64 + jq * 16;
    float Tr[16];
#pragma unroll
    for (int jj = 0; jj < 16; ++jj) Tr[jj] = 0.f;
    for (int k = 0; k < 64; ++k) {
        short8 w0 = *(const short8*)(&Wsel[k * 512 + jbase]);
        short8 w1 = *(const short8*)(&Wsel[k * 512 + jbase + 8]);
        float g = Gs[c * 68 + k];
#pragma unroll
        for (int jj = 0; jj < 8; ++jj) {
            Tr[jj]     += g * bf2f((u16)w0[jj]);
            Tr[8 + jj] += g * bf2f((u16)w1[jj]);
        }
    }
    if (sel == 0) {
#pragma unroll
        for (int q = 0; q < 4; ++q)
            *(float4*)(&T[(size_t)(b * 64 + c) * 512 + jbase + 4 * q]) =
                make_float4(Tr[4 * q], Tr[4 * q + 1], Tr[4 * q + 2], Tr[4 * q + 3]);
    }
    {   // products W[c,j]*T[c,j] for norm
        short8 wc0 = *(const short8*)(&Wsel[c * 512 + jbase]);
        short8 wc1 = *(const short8*)(&Wsel[c * 512 + jbase + 8]);
#pragma unroll
        for (int jj = 0; jj < 8; ++jj) {
            Ps[c * 68 + jq * 16 + jj]     = bf2f((u16)wc0[jj]) * Tr[jj];
            Ps[c * 68 + jq * 16 + 8 + jj] = bf2f((u16)wc1[jj]) * Tr[8 + jj];
        }
    }
    __syncthreads();
    if (t < 64) {
        float s = 0.f;
        for (int cc = 0; cc < 64; ++cc) s += Ps[cc * 68 + t];
        float n = fmaxf(sqrtf(fmaxf(s, 0.f)), 1e-12f);
        (sel ? nk : nq)[b * 512 + jg * 64 + t] = n;
    }
}

// ---------------------------------------------------------------------------
// K4: blocks 0..15 fused attn->softmax->P->Weff (atomicAdd); 16..1039 conv1.
__global__ __launch_bounds__(256) void k_mid2(
    const u16* __restrict__ wkb, const u16* __restrict__ wpb, const u16* __restrict__ wvb,
    const u16* __restrict__ rsb,
    const float* __restrict__ T, const float* __restrict__ nq, const float* __restrict__ nk,
    float* __restrict__ Weff,
    const u16* __restrict__ pbuf, const u16* __restrict__ wpe1, u16* __restrict__ tbuf) {
    __shared__ __align__(16) char shm[53248];
    int blk = blockIdx.x, t = threadIdx.x;
    if (blk < 16) {
        float* Ts    = (float*)shm;              // 17408 B, later Pls
        float* attns = (float*)(shm + 17408);    // 17408 B
        u16*   Wks   = (u16*)(shm + 34816);      // 9216 B, later Wvs
        u16*   Wpjs  = (u16*)(shm + 44032);      // 9216 B
        float* Pls = Ts;
        u16*   Wvs = Wks;
        int b = blk >> 3, h = blk & 7;
        {   // cooperative loads
            int c = t >> 2, j0 = (t & 3) * 16;
#pragma unroll
            for (int q = 0; q < 4; ++q)
                *(float4*)(&Ts[c * 68 + j0 + 4 * q]) =
                    *(const float4*)(&T[(size_t)(b * 64 + c) * 512 + h * 64 + j0 + 4 * q]);
            *(short8*)(&Wks[c * 72 + j0])     = *(const short8*)(&wkb[c * 512 + h * 64 + j0]);
            *(short8*)(&Wks[c * 72 + j0 + 8]) = *(const short8*)(&wkb[c * 512 + h * 64 + j0 + 8]);
            *(short8*)(&Wpjs[c * 72 + j0])     = *(const short8*)(&wpb[(h * 64 + c) * 64 + j0]);
            *(short8*)(&Wpjs[c * 72 + j0 + 8]) = *(const short8*)(&wpb[(h * 64 + c) * 64 + j0 + 8]);
        }
        __syncthreads();
        {   // logits + softmax -> attns
            int i = t >> 2, jq = t & 3;
            float L[16];
#pragma unroll
            for (int jj = 0; jj < 16; ++jj) L[jj] = 0.f;
            for (int c = 0; c < 64; ++c) {
                float wk = bf2f(Wks[c * 72 + i]);
#pragma unroll
                for (int q = 0; q < 4; ++q) {
                    float4 tv = *(const float4*)(&Ts[c * 68 + jq * 16 + 4 * q]);
                    L[4 * q + 0] += wk * tv.x;
                    L[4 * q + 1] += wk * tv.y;
                    L[4 * q + 2] += wk * tv.z;
                    L[4 * q + 3] += wk * tv.w;
                }
            }
            float rs = bf2f(rsb[h]);
            float nki = nk[b * 512 + h * 64 + i];
            float nqv[16];
#pragma unroll
            for (int q = 0; q < 4; ++q) {
                float4 nv = *(const float4*)(&nq[b * 512 + h * 64 + jq * 16 + 4 * q]);
                nqv[4 * q] = nv.x; nqv[4 * q + 1] = nv.y;
                nqv[4 * q + 2] = nv.z; nqv[4 * q + 3] = nv.w;
            }
            float m = -1e30f;
#pragma unroll
            for (int jj = 0; jj < 16; ++jj) {
                L[jj] = L[jj] * rs / (nki * nqv[jj]);
                m = fmaxf(m, L[jj]);
            }
            m = fmaxf(m, __shfl_xor(m, 1));
            m = fmaxf(m, __shfl_xor(m, 2));
            float s = 0.f;
#pragma unroll
            for (int jj = 0; jj < 16; ++jj) {
                L[jj] = __expf(L[jj] - m);
                s += L[jj];
            }
            s += __shfl_xor(s, 1);
            s += __shfl_xor(s, 2);
            float inv = 1.f / s;
#pragma unroll
            for (int q = 0; q < 4; ++q)
                *(float4*)(&attns[i * 68 + jq * 16 + 4 * q]) =
                    make_float4(L[4 * q] * inv, L[4 * q + 1] * inv,
                                L[4 * q + 2] * inv, L[4 * q + 3] * inv);
        }
        __syncthreads();
        {   // Wvs load + P = attn^T @ Wproj_h  -> Pls (overwrites Ts)
            int c = t >> 2, j0 = (t & 3) * 16;
            *(short8*)(&Wvs[c * 72 + j0])     = *(const short8*)(&wvb[c * 512 + h * 64 + j0]);
            *(short8*)(&Wvs[c * 72 + j0 + 8]) = *(const short8*)(&wvb[c * 512 + h * 64 + j0 + 8]);
            int j = t >> 2, oq = t & 3;
            float Pl[16];
#pragma unroll
            for (int jj = 0; jj < 16; ++jj) Pl[jj] = 0.f;
            for (int i2 = 0; i2 < 64; ++i2) {
                float a = attns[i2 * 68 + j];
                short8 w0 = *(const short8*)(&Wpjs[i2 * 72 + oq * 16]);
                short8 w1 = *(const short8*)(&Wpjs[i2 * 72 + oq * 16 + 8]);
#pragma unroll
                for (int jj = 0; jj < 8; ++jj) {
                    Pl[jj]     += a * bf2f((u16)w0[jj]);
                    Pl[8 + jj] += a * bf2f((u16)w1[jj]);
                }
            }
#pragma unroll
            for (int q = 0; q < 4; ++q)
                *(float4*)(&Pls[j * 68 + oq * 16 + 4 * q]) =
                    make_float4(Pl[4 * q], Pl[4 * q + 1], Pl[4 * q + 2], Pl[4 * q + 3]);
        }
        __syncthreads();
        {   // Weff partial: Wv_h @ P -> atomicAdd
            int c = t >> 2, oq = t & 3;
            float acc[16];
#pragma unroll
            for (int jj = 0; jj < 16; ++jj) acc[jj] = 0.f;
            for (int j2 = 0; j2 < 64; ++j2) {
                float wv = bf2f(Wvs[c * 72 + j2]);
#pragma unroll
                for (int q = 0; q < 4; ++q) {
                    float4 pv = *(const float4*)(&Pls[j2 * 68 + oq * 16 + 4 * q]);
                    acc[4 * q + 0] += wv * pv.x;
                    acc[4 * q + 1] += wv * pv.y;
                    acc[4 * q + 2] += wv * pv.z;
                    acc[4 * q + 3] += wv * pv.w;
                }
            }
            float* W = Weff + b * 4096 + c * 64 + oq * 16;
#pragma unroll
            for (int jj = 0; jj < 16; ++jj) atomicAdd(&W[jj], acc[jj]);
        }
        return;
    }
    // ---- conv1 (proven round-4 body), cb = blk - 16 ----
    u16* sm = (u16*)shm;                       // 204*72 u16 = 29376 B
    int cb = blk - 16;
    int b  = cb >> 9;
    int ty = (cb >> 3) & 63;
    int tx = cb & 7;
    int gy0 = ty * 4, gx0 = tx * 32;

    for (int i = t; i < 1632; i += 256) {
        int px = i >> 3, ch = i & 7;
        int hy = px / 34, hx = px - hy * 34;
        int gy = gy0 + hy - 1, gx = gx0 + hx - 1;
        uint4 v = make_uint4(0, 0, 0, 0);
        if ((unsigned)gy < 256u && (unsigned)gx < 256u)
            v = *(const uint4*)(pbuf + ((size_t)((b << 16) + (gy << 8) + gx)) * 64 + ch * 8);
        *(uint4*)(&sm[px * 72 + ch * 8]) = v;
    }
    int oct = t & 7;
    float w[8][9];
#pragma unroll
    for (int j = 0; j < 8; ++j)
#pragma unroll
        for (int k = 0; k < 9; ++k) w[j][k] = bf2f(wpe1[(oct * 8 + j) * 9 + k]);
    __syncthreads();

#pragma unroll
    for (int s = 0; s < 4; ++s) {
        int lp = (t >> 3) + s * 32;
        int ly = lp >> 5, lx = lp & 31;
        float acc[8] = {0.f, 0.f, 0.f, 0.f, 0.f, 0.f, 0.f, 0.f};
#pragma unroll
        for (int dy = 0; dy < 3; ++dy)
#pragma unroll
            for (int dx = 0; dx < 3; ++dx) {
                int hp = (ly + dy) * 34 + lx + dx;
                uint4 v = *(const uint4*)(&sm[hp * 72 + oct * 8]);
                float f[8];
                unpack8(v, f);
                int tap = dy * 3 + dx;
#pragma unroll
                for (int j = 0; j < 8; ++j) acc[j] += f[j] * w[j][tap];
            }
        u32 pk[4];
#pragma unroll
        for (int q = 0; q < 4; ++q)
            pk[q] = pk2(gelu_exact(acc[2 * q]), gelu_exact(acc[2 * q + 1]));
        size_t gpix = (size_t)(b << 16) + ((size_t)(gy0 + ly) << 8) + gx0 + lx;
        *(uint4*)(tbuf + gpix * 64 + oct * 8) = make_uint4(pk[0], pk[1], pk[2], pk[3]);
    }
}

// ---------------------------------------------------------------------------
// K5: out = xb @ Weff[b] + bproj + dwconv3x3(tbuf, Wpe2) (proven round-4 body)
__global__ __launch_bounds__(256) void k_final(const u16* __restrict__ xb,
                                               const u16* __restrict__ tbuf,
                                               const float* __restrict__ Weff,
                                               const u16* __restrict__ wpe2,
                                               const u16* __restrict__ bproj,
                                               float* __restrict__ out) {
    __shared__ u16 sm[204 * 72];
    __shared__ float stage[128 * 68];
    int t = threadIdx.x;
    int blk = blockIdx.x;
    int b  = blk >> 9;
    int ty = (blk >> 3) & 63;
    int tx = blk & 7;
    int gy0 = ty * 4, gx0 = tx * 32;

    for (int i = t; i < 1632; i += 256) {
        int px = i >> 3, ch = i & 7;
        int hy = px / 34, hx = px - hy * 34;
        int gy = gy0 + hy - 1, gx = gx0 + hx - 1;
        uint4 v = make_uint4(0, 0, 0, 0);
        if ((unsigned)gy < 256u && (unsigned)gx < 256u)
            v = *(const uint4*)(tbuf + ((size_t)((b << 16) + (gy << 8) + gx)) * 64 + ch * 8);
        *(uint4*)(&sm[px * 72 + ch * 8]) = v;
    }
    int oct = t & 7;
    {
        float w[8][9];
#pragma unroll
        for (int j = 0; j < 8; ++j)
#pragma unroll
            for (int k = 0; k < 9; ++k) w[j][k] = bf2f(wpe2[(oct * 8 + j) * 9 + k]);
        __syncthreads();
#pragma unroll
        for (int s = 0; s < 4; ++s) {
            int lp = (t >> 3) + s * 32;
            int ly = lp >> 5, lx = lp & 31;
            float acc[8] = {0.f, 0.f, 0.f, 0.f, 0.f, 0.f, 0.f, 0.f};
#pragma unroll
            for (int dy = 0; dy < 3; ++dy)
#pragma unroll
                for (int dx = 0; dx < 3; ++dx) {
                    int hp = (ly + dy) * 34 + lx + dx;
                    uint4 v = *(const uint4*)(&sm[hp * 72 + oct * 8]);
                    float f[8];
                    unpack8(v, f);
                    int tap = dy * 3 + dx;
#pragma unroll
                    for (int j = 0; j < 8; ++j) acc[j] += f[j] * w[j][tap];
                }
#pragma unroll
            for (int j = 0; j < 8; ++j)
                stage[lp * 68 + oct * 8 + j] = acc[j];
        }
    }
    __syncthreads();

    int lane = t & 63, wv = t >> 6;
    int col = lane & 15, quad = lane >> 4;
    const float* W = Weff + b * 4096;
    short8 bf[2][4];
#pragma unroll
    for (int kh = 0; kh < 2; ++kh)
#pragma unroll
        for (int nt = 0; nt < 4; ++nt) {
            short8 v;
#pragma unroll
            for (int j = 0; j < 8; ++j)
                v[j] = (short)f2bf(W[(kh * 32 + quad * 8 + j) * 64 + nt * 16 + col]);
            bf[kh][nt] = v;
        }
    float bias[4];
#pragma unroll
    for (int nt = 0; nt < 4; ++nt) bias[nt] = bf2f(bproj[nt * 16 + col]);

#pragma unroll
    for (int g = 0; g < 2; ++g) {
        int grp = wv * 2 + g;
        int ly = grp >> 1;
        int lxb = (grp & 1) * 16;
        size_t rowpix = (size_t)(b << 16) + ((size_t)(gy0 + ly) << 8) + gx0;
        const short8* ap = (const short8*)(xb + (rowpix + lxb + col) * 64);
        short8 a0 = ap[quad];
        short8 a1 = ap[4 + quad];
#pragma unroll
        for (int nt = 0; nt < 4; ++nt) {
            f32x4 acc = {0.f, 0.f, 0.f, 0.f};
            acc = __builtin_amdgcn_mfma_f32_16x16x32_bf16(a0, bf[0][nt], acc, 0, 0, 0);
            acc = __builtin_amdgcn_mfma_f32_16x16x32_bf16(a1, bf[1][nt], acc, 0, 0, 0);
#pragma unroll
            for (int r = 0; r < 4; ++r) {
                int lp = ly * 32 + lxb + quad * 4 + r;
                stage[lp * 68 + nt * 16 + col] += acc[r] + bias[nt];
            }
        }
    }
    __syncthreads();

#pragma unroll
    for (int k = 0; k < 8; ++k) {
        int linear = k * 256 + t;
        int px = linear >> 4, c4 = linear & 15;
        int ly = px >> 5, lx = px & 31;
        float4 v = *(const float4*)(&stage[px * 68 + c4 * 4]);
        size_t gpix = (size_t)(b << 16) + ((size_t)(gy0 + ly) << 8) + gx0 + lx;
        *(float4*)(out + gpix * 64 + c4 * 4) = v;
    }
}

// ---------------------------------------------------------------------------
extern "C" void kernel_launch(void* const* d_in, const int* in_sizes, int n_in,
                              void* d_out, int out_size, void* d_ws, size_t ws_size,
                              hipStream_t stream) {
    const float* x = (const float*)d_in[0];
    float* out = (float*)d_out;

    char* w = (char*)d_ws;
    size_t off = 0;
    auto alloc = [&](size_t bytes) -> void* {
        void* p = w + off;
        off += (bytes + 255) & ~(size_t)255;
        return p;
    };
    u16* xb = (u16*)alloc((size_t)16777216 * 2);
    u16* wb = (u16*)alloc((size_t)165128 * 2);
    u16* wqb = wb;
    u16* wkb = wqb + 32768;
    u16* wvb = wkb + 32768;
    u16* rsb = wvb + 32768;
    u16* wpb = rsb + 8;
    u16* bpb = wpb + 32768;
    u16* wcb = bpb + 64;
    u16* bcb = wcb + 32768;
    u16* p1b = bcb + 64;
    u16* p2b = p1b + 576;
    (void)wcb;

    float* partials = (float*)alloc((size_t)256 * 4096 * 4);
    float* G        = (float*)alloc((size_t)2 * 4096 * 4);
    float* T        = (float*)alloc((size_t)2 * 64 * 512 * 4);
    float* nq       = (float*)alloc((size_t)2 * 512 * 4);
    float* nk       = (float*)alloc((size_t)2 * 512 * 4);
    float* Weff     = (float*)alloc((size_t)2 * 4096 * 4);
    float* Wpos     = (float*)alloc((size_t)4096 * 4);
    u16*   pbuf     = (u16*)alloc((size_t)2 * 65536 * 64 * 2);
    u16*   tbuf     = (u16*)alloc((size_t)2 * 65536 * 64 * 2);

    hipLaunchKernelGGL(k_front, dim3(595), dim3(256), 0, stream,
                       x,
                       (const float*)d_in[1], (const float*)d_in[2], (const float*)d_in[3],
                       (const float*)d_in[4], (const float*)d_in[5], (const float*)d_in[6],
                       (const float*)d_in[7], (const float*)d_in[8], (const float*)d_in[9],
                       (const float*)d_in[10],
                       (u32*)wb, Wpos, xb, partials);
    hipLaunchKernelGGL(k_mid1, dim3(544), dim3(256), 0, stream,
                       partials, G, Weff, xb, Wpos, bcb, pbuf);
    hipLaunchKernelGGL(k_gwqk_norms, dim3(32), dim3(256), 0, stream,
                       G, wqb, wkb, T, nq, nk);
    hipLaunchKernelGGL(k_mid2, dim3(1040), dim3(256), 0, stream,
                       wkb, wpb, wvb, rsb, T, nq, nk, Weff, pbuf, p1b, tbuf);
    hipLaunchKernelGGL(k_final, dim3(1024), dim3(256), 0, stream,
                       xb, tbuf, Weff, p2b, bpb, out);
}